// Round 1
// baseline (1052.813 us; speedup 1.0000x reference)
//
#include <hip/hip_runtime.h>
#include <stdint.h>

// ---------------------------------------------------------------------------
// Binary net:  conv0(1->64,3x3) -> prelu -> bn -> bin
//              conv1(64->128,3x3) -> prelu -> bn -> bin
//              fc0(100352->1024)  -> prelu -> bn -> bin
//              fc1(1024->10)      -> prelu -> bn -> *scale
// All inner binarize(bn(x)) collapse to sign(v*A_c + B_c).
// ---------------------------------------------------------------------------

static constexpr int BATCH = 256;
static constexpr int HWPX  = 784;     // 28*28
static constexpr int C0    = 64;
static constexpr int C1    = 128;
static constexpr int K0    = 100352;  // C1*HWPX
static constexpr int KW    = 1568;    // K0/64 words
static constexpr int N1    = 1024;
static constexpr int KSPLIT= 16;
static constexpr int JW    = 98;      // KW/KSPLIT
static constexpr int SUBC  = 14;      // words per LDS subchunk
static constexpr int NSUB  = 7;       // JW/SUBC
static constexpr unsigned ZCAP = 65536;

__device__ __forceinline__ float fsign(float v){
    return (v > 0.f) ? 1.f : ((v < 0.f) ? -1.f : 0.f);
}

// ---- conv block 0: sign(x) conv3x3 sign(cw0), prelu, accumulate bn stats ----
__global__ __launch_bounds__(256) void k_conv0(const float* __restrict__ x,
        const float* __restrict__ cw0, const float* __restrict__ cp0,
        int8_t* __restrict__ h0s, double* __restrict__ S0, double* __restrict__ Q0)
{
    __shared__ float img[30][30];           // zero-padded signed image
    __shared__ float redS[4][64];
    __shared__ float redQ[4][64];
    int b = blockIdx.x;
    int tid = threadIdx.x;
    for (int i = tid; i < 900; i += 256) ((float*)img)[i] = 0.f;
    __syncthreads();
    for (int i = tid; i < 784; i += 256) {
        float v = x[b*784 + i];
        img[1 + i/28][1 + i%28] = fsign(v);
    }
    __syncthreads();
    int lane = tid & 63, wv = tid >> 6;   // lane = out channel
    float wsg[9];
    #pragma unroll
    for (int t = 0; t < 9; t++) wsg[t] = fsign(cw0[lane*9 + t]);
    float a = cp0[lane];
    float accS = 0.f, accQ = 0.f;
    for (int i = 0; i < 196; i++) {
        int p = wv*196 + i;
        int y = p / 28, xx = p % 28;
        float s = 0.f;
        #pragma unroll
        for (int dy = 0; dy < 3; dy++)
            #pragma unroll
            for (int dx = 0; dx < 3; dx++)
                s += img[y+dy][xx+dx] * wsg[dy*3+dx];
        h0s[(size_t)(b*784 + p)*64 + lane] = (int8_t)(int)s;   // exact small int
        float v = (s >= 0.f) ? s : a*s;
        accS += v; accQ += v*v;
    }
    redS[wv][lane] = accS; redQ[wv][lane] = accQ;
    __syncthreads();
    if (tid < 64) {
        double s = (double)redS[0][tid] + redS[1][tid] + redS[2][tid] + redS[3][tid];
        double q = (double)redQ[0][tid] + redQ[1][tid] + redQ[2][tid] + redQ[3][tid];
        atomicAdd(&S0[tid], s);
        atomicAdd(&Q0[tid], q);
    }
}

// ---- finalize bn -> affine threshold coefficients (A,B) in f64 ----
__global__ void k_bnfin(const double* __restrict__ S, const double* __restrict__ Q,
        const float* __restrict__ g, const float* __restrict__ bb,
        double* __restrict__ AB, int C, double invN)
{
    int c = threadIdx.x;
    if (c >= C) return;
    double mean = S[c] * invN;
    double var  = Q[c] * invN - mean*mean;
    if (var < 0.0) var = 0.0;
    double A = (double)g[c] / sqrt(var + 1e-5);
    AB[c]     = A;
    AB[C + c] = (double)bb[c] - mean*A;
}

// ---- pack conv1 input: one u64 per pixel (bit c = negative) ----
__global__ __launch_bounds__(256) void k_pack_h0(const int8_t* __restrict__ h0s,
        const float* __restrict__ cp0, const double* __restrict__ AB,
        uint64_t* __restrict__ hp)
{
    int idx = blockIdx.x * 4 + (threadIdx.x >> 6);   // = b*784+p
    int lane = threadIdx.x & 63;
    float s = (float)h0s[(size_t)idx*64 + lane];
    float a = cp0[lane];
    float v = (s >= 0.f) ? s : a*s;
    double t = fma((double)v, AB[lane], AB[64 + lane]);
    uint64_t m = __ballot(t < 0.0);
    if (lane == 0) hp[idx] = m;
}

// ---- pack conv1 weights: neg mask + nonzero mask per (oc, tap) ----
__global__ __launch_bounds__(256) void k_pack_w1(const float* __restrict__ cw1,
        uint64_t* __restrict__ wn1, uint64_t* __restrict__ wnz1)
{
    int idx = blockIdx.x*4 + (threadIdx.x >> 6);     // (oc*9 + t)
    int lane = threadIdx.x & 63;                     // lane = in channel
    int oc = idx / 9, t = idx % 9;
    float w = cw1[oc*576 + lane*9 + t];
    uint64_t n = __ballot(w < 0.f);
    uint64_t z = __ballot(w != 0.f);
    if (lane == 0) { wn1[idx] = n; wnz1[idx] = z; }
}

// ---- conv1 via XOR/popcount, write raw int16 sums ----
__global__ __launch_bounds__(256) void k_conv1(const uint64_t* __restrict__ hp,
        const uint64_t* __restrict__ wn1, const uint64_t* __restrict__ wnz1,
        int16_t* __restrict__ h1s)
{
    int bid = blockIdx.x;
    int ocg = bid & 15;
    int ptg = (bid >> 4) & 3;
    int b   = bid >> 6;
    int wv = threadIdx.x >> 6, lane = threadIdx.x & 63;
    int pt = ptg*4 + wv;
    if (pt >= 13) return;
    int p = pt*64 + lane;
    bool pvalid = p < 784;
    int pcl = pvalid ? p : 783;
    int y = pcl / 28, xx = pcl % 28;
    uint64_t nb[9]; unsigned vmask = 0;
    #pragma unroll
    for (int dy = 0; dy < 3; dy++)
        #pragma unroll
        for (int dx = 0; dx < 3; dx++) {
            int t = dy*3+dx;
            int yy = y + dy - 1, xv = xx + dx - 1;
            bool ok = (yy >= 0 && yy < 28 && xv >= 0 && xv < 28);
            nb[t] = hp[b*784 + (ok ? (yy*28+xv) : 0)];
            if (ok) vmask |= 1u << t;
        }
    #pragma unroll
    for (int o = 0; o < 8; o++) {
        int oc = ocg*8 + o;
        int base = oc*9;
        int acc = 0;
        #pragma unroll
        for (int t = 0; t < 9; t++) {
            uint64_t wn = wn1[base+t], wz = wnz1[base+t];
            if (vmask & (1u<<t))
                acc += (int)__popcll(wz) - 2*(int)__popcll((nb[t] ^ wn) & wz);
        }
        if (pvalid) h1s[((size_t)b*128 + oc)*784 + p] = (int16_t)acc;
    }
}

// ---- bn1 statistics over h1s ----
__global__ __launch_bounds__(256) void k_stats1(const int16_t* __restrict__ h1s,
        const float* __restrict__ cp1, double* __restrict__ S1, double* __restrict__ Q1)
{
    int oc = blockIdx.x >> 3, bg = blockIdx.x & 7;
    int tid = threadIdx.x;
    float a = cp1[oc];
    float accS = 0.f, accQ = 0.f;
    for (int i = tid; i < 32*784; i += 256) {
        int b = bg*32 + i/784, p = i%784;
        float s = (float)h1s[((size_t)b*128+oc)*784 + p];
        float v = (s >= 0.f) ? s : a*s;
        accS += v; accQ += v*v;
    }
    __shared__ double rs[256], rq[256];
    rs[tid] = accS; rq[tid] = accQ;
    __syncthreads();
    for (int off = 128; off > 0; off >>= 1) {
        if (tid < off) { rs[tid] += rs[tid+off]; rq[tid] += rq[tid+off]; }
        __syncthreads();
    }
    if (tid == 0) { atomicAdd(&S1[oc], rs[0]); atomicAdd(&Q1[oc], rq[0]); }
}

// ---- pack fc0 activations, transposed: ap_t[word j][batch b] ----
__global__ __launch_bounds__(256) void k_pack_a0(const int16_t* __restrict__ h1s,
        const float* __restrict__ cp1, const double* __restrict__ AB,
        uint64_t* __restrict__ ap_t)
{
    int bb = blockIdx.x / 392;
    int jg = blockIdx.x % 392;
    int j = jg*4 + (threadIdx.x >> 6);
    int lane = threadIdx.x & 63;
    int k = j*64 + lane;                  // k = oc*784 + p (flatten order)
    int oc = k / 784;
    int p  = k - oc*784;
    float s = (float)h1s[((size_t)bb*128 + oc)*784 + p];
    float a = cp1[oc];
    float v = (s >= 0.f) ? s : a*s;
    double t = fma((double)v, AB[oc], AB[128+oc]);
    uint64_t m = __ballot(t < 0.0);
    if (lane == 0) ap_t[(size_t)j*256 + bb] = m;
}

// ---- fused fc0: read fw0 fp32, ballot-pack in LDS, XOR-popcount GEMM ----
__global__ __launch_bounds__(256) void k_fc0(const float* __restrict__ fw0,
        const uint64_t* __restrict__ ap_t,
        int* __restrict__ pcpart,         // [KSPLIT][N1][BATCH]
        unsigned* __restrict__ zcnt, uint64_t* __restrict__ zlist)
{
    __shared__ uint64_t wL[SUBC][64];
    __shared__ uint64_t apL[SUBC][256];
    int bid = blockIdx.x;
    int nt = bid & 15;
    int ks = bid >> 4;
    int tid = threadIdx.x;
    int wv = tid >> 6, lane = tid & 63;
    int bq = tid & 31;          // b = bq + 32*i
    int nq = tid >> 5;          // n = n0 + nq + 8*k
    int n0 = nt*64;
    int pc[8][8];
    #pragma unroll
    for (int i=0;i<8;i++)
        #pragma unroll
        for (int k=0;k<8;k++) pc[i][k]=0;
    int jbase = ks*JW;
    for (int c = 0; c < NSUB; c++) {
        int j0 = jbase + c*SUBC;
        #pragma unroll
        for (int r = 0; r < SUBC; r++)
            apL[r][tid] = ap_t[(size_t)(j0 + r)*256 + tid];
        for (int idx = wv; idx < SUBC*64; idx += 4) {
            int n = idx & 63, jj = idx >> 6;
            float w = fw0[(size_t)(n0 + n)*K0 + (size_t)(j0 + jj)*64 + lane];
            uint64_t neg = __ballot(w < 0.f);
            uint64_t zz  = __ballot(w == 0.f);
            if (lane == 0) {
                wL[jj][n] = neg;
                if (zz) {   // rare: exact-zero weights; record for correction
                    unsigned id = atomicAdd(zcnt, 1u);
                    if (id < ZCAP) {
                        zlist[2*id]   = ((uint64_t)(unsigned)(n0+n) << 32) | (unsigned)(j0+jj);
                        zlist[2*id+1] = zz;
                    }
                }
            }
        }
        __syncthreads();
        #pragma unroll
        for (int jj = 0; jj < SUBC; jj++) {
            uint64_t aw[8], ww[8];
            #pragma unroll
            for (int i = 0; i < 8; i++) aw[i] = apL[jj][bq + 32*i];
            #pragma unroll
            for (int k = 0; k < 8; k++) ww[k] = wL[jj][nq + 8*k];
            #pragma unroll
            for (int i = 0; i < 8; i++)
                #pragma unroll
                for (int k = 0; k < 8; k++)
                    pc[i][k] += (int)__popcll(aw[i] ^ ww[k]);
        }
        __syncthreads();
    }
    #pragma unroll
    for (int k = 0; k < 8; k++) {
        int n = n0 + nq + 8*k;
        #pragma unroll
        for (int i = 0; i < 8; i++)
            pcpart[((size_t)ks*N1 + n)*BATCH + (bq + 32*i)] = pc[i][k];
    }
}

// ---- correction for exact-zero fw0 entries ----
__global__ __launch_bounds__(256) void k_corr(const unsigned* __restrict__ zcnt,
        const uint64_t* __restrict__ zlist, const uint64_t* __restrict__ ap_t,
        int* __restrict__ corr)
{
    unsigned cnt = *zcnt; if (cnt > ZCAP) cnt = ZCAP;
    int b = threadIdx.x;
    for (unsigned e = blockIdx.x; e < cnt; e += gridDim.x) {
        uint64_t key = zlist[2*e], zm = zlist[2*e+1];
        int n = (int)(key >> 32), j = (int)(key & 0xffffffffu);
        uint64_t a = ap_t[(size_t)j*256 + b];
        int c = 2*(int)__popcll(a & zm) - (int)__popcll(zm);
        atomicAdd(&corr[b*N1 + n], c);
    }
}

// ---- fc0 epilogue: combine partials, prelu, bn stats per feature, binarize ----
__global__ __launch_bounds__(256) void k_fc0ep(const int* __restrict__ pcpart,
        const int* __restrict__ corr, const float* __restrict__ fp0,
        const float* __restrict__ fg0, const float* __restrict__ fb0,
        float* __restrict__ af)
{
    int n = blockIdx.x, b = threadIdx.x;
    int pc = 0;
    #pragma unroll
    for (int ks = 0; ks < KSPLIT; ks++) pc += pcpart[((size_t)ks*N1 + n)*BATCH + b];
    int s = K0 - 2*pc + corr[b*N1 + n];
    float a = fp0[n];
    float v = (s >= 0) ? (float)s : a*(float)s;
    __shared__ double rs[256], rq[256];
    rs[b] = v; rq[b] = (double)v*(double)v;
    __syncthreads();
    for (int off=128; off>0; off>>=1){
        if (b<off){ rs[b]+=rs[b+off]; rq[b]+=rq[b+off]; }
        __syncthreads();
    }
    __shared__ double AB[2];
    if (b == 0) {
        double mean = rs[0] / 256.0;
        double var = rq[0] / 256.0 - mean*mean;
        if (var < 0.0) var = 0.0;
        double A = (double)fg0[n] / sqrt(var + 1e-5);
        AB[0] = A; AB[1] = (double)fb0[n] - mean*A;
    }
    __syncthreads();
    double t = fma((double)v, AB[0], AB[1]);
    af[(size_t)n*256 + b] = (t > 0.0) ? 1.f : ((t < 0.0) ? -1.f : 0.f);
}

// ---- fc1 partial dots (k-split) ----
__global__ __launch_bounds__(256) void k_fc1a(const float* __restrict__ af,
        const float* __restrict__ fw1, float* __restrict__ part9)
{
    __shared__ float swL[10][32];
    int ks = blockIdx.x, b = threadIdx.x;
    for (int i = b; i < 320; i += 256) {
        int j = i / 32, kk = i % 32;
        swL[j][kk] = fsign(fw1[j*1024 + ks*32 + kk]);
    }
    __syncthreads();
    float acc[10];
    #pragma unroll
    for (int j=0;j<10;j++) acc[j]=0.f;
    for (int kk = 0; kk < 32; kk++) {
        float a = af[(size_t)(ks*32+kk)*256 + b];
        #pragma unroll
        for (int j=0;j<10;j++) acc[j] += a * swL[j][kk];
    }
    #pragma unroll
    for (int j=0;j<10;j++) part9[((size_t)ks*256 + b)*10 + j] = acc[j];
}

// ---- fc1 finish: prelu, bn over batch, scale ----
__global__ __launch_bounds__(256) void k_fc1b(const float* __restrict__ part9,
        const float* __restrict__ fp1, const float* __restrict__ fg1,
        const float* __restrict__ fb1, const float* __restrict__ scale,
        float* __restrict__ out)
{
    int b = threadIdx.x;
    float v[10];
    #pragma unroll
    for (int j=0;j<10;j++) v[j]=0.f;
    for (int ks=0; ks<32; ks++)
        #pragma unroll
        for (int j=0;j<10;j++) v[j] += part9[((size_t)ks*256+b)*10 + j];
    #pragma unroll
    for (int j=0;j<10;j++){
        float a = fp1[j];
        v[j] = (v[j] >= 0.f) ? v[j] : a*v[j];
    }
    __shared__ double sv[256];
    __shared__ double AB[2][10];
    for (int j=0;j<10;j++){
        sv[b] = (double)v[j];
        __syncthreads();
        for (int off=128;off>0;off>>=1){ if(b<off) sv[b]+=sv[b+off]; __syncthreads(); }
        double mean = sv[0]/256.0;
        __syncthreads();
        double d = (double)v[j]-mean;
        sv[b] = d*d;
        __syncthreads();
        for (int off=128;off>0;off>>=1){ if(b<off) sv[b]+=sv[b+off]; __syncthreads(); }
        if (b==0){
            double var = sv[0]/256.0;
            double A = (double)fg1[j]/sqrt(var+1e-5);
            AB[0][j]=A; AB[1][j]=(double)fb1[j] - mean*A;
        }
        __syncthreads();
    }
    float sc = scale[0];
    #pragma unroll
    for (int j=0;j<10;j++)
        out[b*10+j] = (float)fma((double)v[j], AB[0][j], AB[1][j]) * sc;
}

extern "C" void kernel_launch(void* const* d_in, const int* in_sizes, int n_in,
                              void* d_out, int out_size, void* d_ws, size_t ws_size,
                              hipStream_t stream)
{
    const float* x    = (const float*)d_in[0];
    const float* cw0  = (const float*)d_in[1];
    const float* cp0  = (const float*)d_in[2];
    const float* cg0  = (const float*)d_in[3];
    const float* cb0  = (const float*)d_in[4];
    const float* cw1  = (const float*)d_in[5];
    const float* cp1  = (const float*)d_in[6];
    const float* cg1  = (const float*)d_in[7];
    const float* cb1  = (const float*)d_in[8];
    const float* fw0  = (const float*)d_in[9];
    const float* fp0  = (const float*)d_in[10];
    const float* fg0  = (const float*)d_in[11];
    const float* fb0  = (const float*)d_in[12];
    const float* fw1  = (const float*)d_in[13];
    const float* fp1  = (const float*)d_in[14];
    const float* fg1  = (const float*)d_in[15];
    const float* fb1  = (const float*)d_in[16];
    const float* scale= (const float*)d_in[17];

    char* ws = (char*)d_ws;
    size_t off = 0;
    auto alloc = [&](size_t bytes)->char* {
        char* r = ws + off; off = (off + bytes + 255) & ~(size_t)255; return r; };

    // zeroed region (contiguous, one memset)
    double*   S0    = (double*)alloc(64*8);
    double*   Q0    = (double*)alloc(64*8);
    double*   S1    = (double*)alloc(128*8);
    double*   Q1    = (double*)alloc(128*8);
    unsigned* zcnt  = (unsigned*)alloc(256);
    int*      corr  = (int*)alloc((size_t)256*1024*4);
    size_t zero_bytes = off;
    // scratch
    double*   A0B0  = (double*)alloc(128*8);
    double*   A1B1  = (double*)alloc(256*8);
    int8_t*   h0s   = (int8_t*)alloc((size_t)256*784*64);
    uint64_t* hp    = (uint64_t*)alloc((size_t)256*784*8);
    int16_t*  h1s   = (int16_t*)alloc((size_t)256*128*784*2);
    uint64_t* ap_t  = (uint64_t*)alloc((size_t)1568*256*8);
    uint64_t* wn1   = (uint64_t*)alloc(1152*8);
    uint64_t* wnz1  = (uint64_t*)alloc(1152*8);
    int*      pcpart= (int*)alloc((size_t)KSPLIT*N1*BATCH*4);
    float*    af    = (float*)alloc((size_t)1024*256*4);
    float*    part9 = (float*)alloc((size_t)32*256*10*4);
    uint64_t* zlist = (uint64_t*)alloc((size_t)ZCAP*16);
    (void)ws_size; (void)in_sizes; (void)n_in; (void)out_size;

    hipMemsetAsync(d_ws, 0, zero_bytes, stream);
    k_conv0 <<<256,   256, 0, stream>>>(x, cw0, cp0, h0s, S0, Q0);
    k_bnfin <<<1,      64, 0, stream>>>(S0, Q0, cg0, cb0, A0B0, 64, 1.0/200704.0);
    k_pack_h0<<<50176,256, 0, stream>>>(h0s, cp0, A0B0, hp);
    k_pack_w1<<<288,  256, 0, stream>>>(cw1, wn1, wnz1);
    k_conv1 <<<16384, 256, 0, stream>>>(hp, wn1, wnz1, h1s);
    k_stats1<<<1024,  256, 0, stream>>>(h1s, cp1, S1, Q1);
    k_bnfin <<<1,     128, 0, stream>>>(S1, Q1, cg1, cb1, A1B1, 128, 1.0/200704.0);
    k_pack_a0<<<100352,256,0, stream>>>(h1s, cp1, A1B1, ap_t);
    k_fc0   <<<256,   256, 0, stream>>>(fw0, ap_t, pcpart, zcnt, zlist);
    k_corr  <<<64,    256, 0, stream>>>(zcnt, zlist, ap_t, corr);
    k_fc0ep <<<1024,  256, 0, stream>>>(pcpart, corr, fp0, fg0, fb0, af);
    k_fc1a  <<<32,    256, 0, stream>>>(af, fw1, part9);
    k_fc1b  <<<1,     256, 0, stream>>>(part9, fp1, fg1, fb1, scale, (float*)d_out);
}

// Round 2
// 428.802 us; speedup vs baseline: 2.4552x; 2.4552x over previous
//
#include <hip/hip_runtime.h>
#include <stdint.h>

// ---------------------------------------------------------------------------
// Binary net:  conv0(1->64,3x3) -> prelu -> bn -> bin
//              conv1(64->128,3x3) -> prelu -> bn -> bin
//              fc0(100352->1024)  -> prelu -> bn -> bin
//              fc1(1024->10)      -> prelu -> bn -> *scale
// All inner binarize(bn(x)) collapse to sign(v*A_c + B_c).
// fc0 = pack fw0 (HBM-bound, high occupancy) + XOR/popcount GEMM (VALU-bound).
// ---------------------------------------------------------------------------

static constexpr int BATCH = 256;
static constexpr int C1    = 128;
static constexpr int K0    = 100352;  // C1*784
static constexpr int KW    = 1568;    // K0/64 words
static constexpr int N1    = 1024;
// fc0 GEMM tiling
static constexpr int KS2   = 49;      // k-splits
static constexpr int JW2   = 32;      // words per split (KW/KS2)
static constexpr int SUB2  = 8;       // words per LDS subchunk
static constexpr int NS2   = 4;       // JW2/SUB2
static constexpr unsigned ZCAP = 65536;

__device__ __forceinline__ float fsign(float v){
    return (v > 0.f) ? 1.f : ((v < 0.f) ? -1.f : 0.f);
}

// ---- conv block 0: sign(x) conv3x3 sign(cw0), prelu, accumulate bn stats ----
__global__ __launch_bounds__(256) void k_conv0(const float* __restrict__ x,
        const float* __restrict__ cw0, const float* __restrict__ cp0,
        int8_t* __restrict__ h0s, double* __restrict__ S0, double* __restrict__ Q0)
{
    __shared__ float img[30][30];
    __shared__ float redS[4][64];
    __shared__ float redQ[4][64];
    int b = blockIdx.x;
    int tid = threadIdx.x;
    for (int i = tid; i < 900; i += 256) ((float*)img)[i] = 0.f;
    __syncthreads();
    for (int i = tid; i < 784; i += 256) {
        float v = x[b*784 + i];
        img[1 + i/28][1 + i%28] = fsign(v);
    }
    __syncthreads();
    int lane = tid & 63, wv = tid >> 6;   // lane = out channel
    float wsg[9];
    #pragma unroll
    for (int t = 0; t < 9; t++) wsg[t] = fsign(cw0[lane*9 + t]);
    float a = cp0[lane];
    float accS = 0.f, accQ = 0.f;
    for (int i = 0; i < 196; i++) {
        int p = wv*196 + i;
        int y = p / 28, xx = p % 28;
        float s = 0.f;
        #pragma unroll
        for (int dy = 0; dy < 3; dy++)
            #pragma unroll
            for (int dx = 0; dx < 3; dx++)
                s += img[y+dy][xx+dx] * wsg[dy*3+dx];
        h0s[(size_t)(b*784 + p)*64 + lane] = (int8_t)(int)s;
        float v = (s >= 0.f) ? s : a*s;
        accS += v; accQ += v*v;
    }
    redS[wv][lane] = accS; redQ[wv][lane] = accQ;
    __syncthreads();
    if (tid < 64) {
        double s = (double)redS[0][tid] + redS[1][tid] + redS[2][tid] + redS[3][tid];
        double q = (double)redQ[0][tid] + redQ[1][tid] + redQ[2][tid] + redQ[3][tid];
        atomicAdd(&S0[tid], s);
        atomicAdd(&Q0[tid], q);
    }
}

// ---- finalize bn -> affine threshold coefficients (A,B) in f64 ----
__global__ void k_bnfin(const double* __restrict__ S, const double* __restrict__ Q,
        const float* __restrict__ g, const float* __restrict__ bb,
        double* __restrict__ AB, int C, double invN)
{
    int c = threadIdx.x;
    if (c >= C) return;
    double mean = S[c] * invN;
    double var  = Q[c] * invN - mean*mean;
    if (var < 0.0) var = 0.0;
    double A = (double)g[c] / sqrt(var + 1e-5);
    AB[c]     = A;
    AB[C + c] = (double)bb[c] - mean*A;
}

// ---- pack conv1 input: one u64 per pixel (bit c = negative) ----
__global__ __launch_bounds__(256) void k_pack_h0(const int8_t* __restrict__ h0s,
        const float* __restrict__ cp0, const double* __restrict__ AB,
        uint64_t* __restrict__ hp)
{
    int idx = blockIdx.x * 4 + (threadIdx.x >> 6);   // = b*784+p
    int lane = threadIdx.x & 63;
    float s = (float)h0s[(size_t)idx*64 + lane];
    float a = cp0[lane];
    float v = (s >= 0.f) ? s : a*s;
    double t = fma((double)v, AB[lane], AB[64 + lane]);
    uint64_t m = __ballot(t < 0.0);
    if (lane == 0) hp[idx] = m;
}

// ---- pack conv1 weights: neg mask + nonzero mask per (oc, tap) ----
__global__ __launch_bounds__(256) void k_pack_w1(const float* __restrict__ cw1,
        uint64_t* __restrict__ wn1, uint64_t* __restrict__ wnz1)
{
    int idx = blockIdx.x*4 + (threadIdx.x >> 6);     // (oc*9 + t)
    int lane = threadIdx.x & 63;                     // lane = in channel
    int oc = idx / 9, t = idx % 9;
    float w = cw1[oc*576 + lane*9 + t];
    uint64_t n = __ballot(w < 0.f);
    uint64_t z = __ballot(w != 0.f);
    if (lane == 0) { wn1[idx] = n; wnz1[idx] = z; }
}

// ---- conv1 via XOR/popcount, write raw int16 sums ----
__global__ __launch_bounds__(256) void k_conv1(const uint64_t* __restrict__ hp,
        const uint64_t* __restrict__ wn1, const uint64_t* __restrict__ wnz1,
        int16_t* __restrict__ h1s)
{
    int bid = blockIdx.x;
    int ocg = bid & 15;
    int ptg = (bid >> 4) & 3;
    int b   = bid >> 6;
    int wv = threadIdx.x >> 6, lane = threadIdx.x & 63;
    int pt = ptg*4 + wv;
    if (pt >= 13) return;
    int p = pt*64 + lane;
    bool pvalid = p < 784;
    int pcl = pvalid ? p : 783;
    int y = pcl / 28, xx = pcl % 28;
    uint64_t nb[9]; unsigned vmask = 0;
    #pragma unroll
    for (int dy = 0; dy < 3; dy++)
        #pragma unroll
        for (int dx = 0; dx < 3; dx++) {
            int t = dy*3+dx;
            int yy = y + dy - 1, xv = xx + dx - 1;
            bool ok = (yy >= 0 && yy < 28 && xv >= 0 && xv < 28);
            nb[t] = hp[b*784 + (ok ? (yy*28+xv) : 0)];
            if (ok) vmask |= 1u << t;
        }
    #pragma unroll
    for (int o = 0; o < 8; o++) {
        int oc = ocg*8 + o;
        int base = oc*9;
        int acc = 0;
        #pragma unroll
        for (int t = 0; t < 9; t++) {
            uint64_t wn = wn1[base+t], wz = wnz1[base+t];
            if (vmask & (1u<<t))
                acc += (int)__popcll(wz) - 2*(int)__popcll((nb[t] ^ wn) & wz);
        }
        if (pvalid) h1s[((size_t)b*128 + oc)*784 + p] = (int16_t)acc;
    }
}

// ---- bn1 statistics over h1s ----
__global__ __launch_bounds__(256) void k_stats1(const int16_t* __restrict__ h1s,
        const float* __restrict__ cp1, double* __restrict__ S1, double* __restrict__ Q1)
{
    int oc = blockIdx.x >> 3, bg = blockIdx.x & 7;
    int tid = threadIdx.x;
    float a = cp1[oc];
    float accS = 0.f, accQ = 0.f;
    for (int i = tid; i < 32*784; i += 256) {
        int b = bg*32 + i/784, p = i%784;
        float s = (float)h1s[((size_t)b*128+oc)*784 + p];
        float v = (s >= 0.f) ? s : a*s;
        accS += v; accQ += v*v;
    }
    __shared__ double rs[256], rq[256];
    rs[tid] = accS; rq[tid] = accQ;
    __syncthreads();
    for (int off = 128; off > 0; off >>= 1) {
        if (tid < off) { rs[tid] += rs[tid+off]; rq[tid] += rq[tid+off]; }
        __syncthreads();
    }
    if (tid == 0) { atomicAdd(&S1[oc], rs[0]); atomicAdd(&Q1[oc], rq[0]); }
}

// ---- pack fc0 activations, transposed: ap_t[word j][batch b] ----
__global__ __launch_bounds__(256) void k_pack_a0(const int16_t* __restrict__ h1s,
        const float* __restrict__ cp1, const double* __restrict__ AB,
        uint64_t* __restrict__ ap_t)
{
    int bb = blockIdx.x / 392;
    int jg = blockIdx.x % 392;
    int j = jg*4 + (threadIdx.x >> 6);
    int lane = threadIdx.x & 63;
    int k = j*64 + lane;                  // k = oc*784 + p (flatten order)
    int oc = k / 784;
    int p  = k - oc*784;
    float s = (float)h1s[((size_t)bb*128 + oc)*784 + p];
    float a = cp1[oc];
    float v = (s >= 0.f) ? s : a*s;
    double t = fma((double)v, AB[oc], AB[128+oc]);
    uint64_t m = __ballot(t < 0.0);
    if (lane == 0) ap_t[(size_t)j*256 + bb] = m;
}

// ---- pack fc0 weights (streaming, transposed wp_t[j][n]) ----
__global__ __launch_bounds__(256) void k_pack_w0(const float* __restrict__ fw0,
        uint64_t* __restrict__ wp_t, unsigned* __restrict__ zcnt,
        uint64_t* __restrict__ zlist)
{
    int j = blockIdx.x;                       // word 0..1567
    int wv = threadIdx.x >> 6, lane = threadIdx.x & 63;
    const float* col = fw0 + (size_t)j*64 + lane;
    int nbase = wv*256;
    for (int i = 0; i < 256; i += 4) {
        int n = nbase + i;
        float w0 = col[(size_t)(n+0)*K0];
        float w1 = col[(size_t)(n+1)*K0];
        float w2 = col[(size_t)(n+2)*K0];
        float w3 = col[(size_t)(n+3)*K0];
        uint64_t g0 = __ballot(w0 < 0.f), z0 = __ballot(w0 == 0.f);
        uint64_t g1 = __ballot(w1 < 0.f), z1 = __ballot(w1 == 0.f);
        uint64_t g2 = __ballot(w2 < 0.f), z2 = __ballot(w2 == 0.f);
        uint64_t g3 = __ballot(w3 < 0.f), z3 = __ballot(w3 == 0.f);
        if (lane == 0) {
            uint64_t* dst = wp_t + (size_t)j*N1 + n;
            dst[0] = g0; dst[1] = g1; dst[2] = g2; dst[3] = g3;
            uint64_t zs[4] = {z0, z1, z2, z3};
            #pragma unroll
            for (int r = 0; r < 4; r++) if (zs[r]) {
                unsigned id = atomicAdd(zcnt, 1u);
                if (id < ZCAP) {
                    zlist[2*id]   = ((uint64_t)(unsigned)(n+r) << 32) | (unsigned)j;
                    zlist[2*id+1] = zs[r];
                }
            }
        }
    }
}

// ---- fc0 XOR/popcount GEMM on packed operands ----
__global__ __launch_bounds__(256) void k_fc0g(const uint64_t* __restrict__ wp_t,
        const uint64_t* __restrict__ ap_t, int16_t* __restrict__ pcpart)
{
    __shared__ uint64_t wL[SUB2][32];
    __shared__ uint64_t apL[SUB2][256];
    int nt = blockIdx.x & 31;     // 32 n-tiles of 32
    int ks = blockIdx.x >> 5;     // 49 k-splits
    int tid = threadIdx.x;
    int bq = tid & 31;            // b = bq + 32*i
    int nq = tid >> 5;            // n = n0 + nq + 8*k
    int n0 = nt*32;
    int pc[8][4];
    #pragma unroll
    for (int i=0;i<8;i++)
        #pragma unroll
        for (int k=0;k<4;k++) pc[i][k]=0;
    int jbase = ks*JW2;
    for (int c = 0; c < NS2; c++) {
        int j0 = jbase + c*SUB2;
        #pragma unroll
        for (int r = 0; r < SUB2; r++)
            apL[r][tid] = ap_t[(size_t)(j0 + r)*256 + tid];
        {
            int jj = tid >> 5, n = tid & 31;
            wL[jj][n] = wp_t[(size_t)(j0 + jj)*N1 + n0 + n];
        }
        __syncthreads();
        #pragma unroll
        for (int jj = 0; jj < SUB2; jj++) {
            uint64_t aw[8], ww[4];
            #pragma unroll
            for (int i = 0; i < 8; i++) aw[i] = apL[jj][bq + 32*i];
            #pragma unroll
            for (int k = 0; k < 4; k++) ww[k] = wL[jj][nq + 8*k];
            #pragma unroll
            for (int i = 0; i < 8; i++)
                #pragma unroll
                for (int k = 0; k < 4; k++)
                    pc[i][k] += (int)__popcll(aw[i] ^ ww[k]);
        }
        __syncthreads();
    }
    #pragma unroll
    for (int k = 0; k < 4; k++) {
        int n = n0 + nq + 8*k;
        #pragma unroll
        for (int i = 0; i < 8; i++)
            pcpart[((size_t)ks*N1 + n)*BATCH + (bq + 32*i)] = (int16_t)pc[i][k];
    }
}

// ---- correction for exact-zero fw0 entries ----
__global__ __launch_bounds__(256) void k_corr(const unsigned* __restrict__ zcnt,
        const uint64_t* __restrict__ zlist, const uint64_t* __restrict__ ap_t,
        int* __restrict__ corr)
{
    unsigned cnt = *zcnt; if (cnt > ZCAP) cnt = ZCAP;
    int b = threadIdx.x;
    for (unsigned e = blockIdx.x; e < cnt; e += gridDim.x) {
        uint64_t key = zlist[2*e], zm = zlist[2*e+1];
        int n = (int)(key >> 32), j = (int)(key & 0xffffffffu);
        uint64_t a = ap_t[(size_t)j*256 + b];
        int c = 2*(int)__popcll(a & zm) - (int)__popcll(zm);
        atomicAdd(&corr[b*N1 + n], c);
    }
}

// ---- fc0 epilogue: combine partials, prelu, bn stats per feature, binarize ----
__global__ __launch_bounds__(256) void k_fc0ep(const int16_t* __restrict__ pcpart,
        const int* __restrict__ corr, const float* __restrict__ fp0,
        const float* __restrict__ fg0, const float* __restrict__ fb0,
        float* __restrict__ af)
{
    int n = blockIdx.x, b = threadIdx.x;
    int pc = 0;
    #pragma unroll
    for (int ks = 0; ks < KS2; ks++) pc += (int)pcpart[((size_t)ks*N1 + n)*BATCH + b];
    int s = K0 - 2*pc + corr[b*N1 + n];
    float a = fp0[n];
    float v = (s >= 0) ? (float)s : a*(float)s;
    __shared__ double rs[256], rq[256];
    rs[b] = v; rq[b] = (double)v*(double)v;
    __syncthreads();
    for (int off=128; off>0; off>>=1){
        if (b<off){ rs[b]+=rs[b+off]; rq[b]+=rq[b+off]; }
        __syncthreads();
    }
    __shared__ double AB[2];
    if (b == 0) {
        double mean = rs[0] / 256.0;
        double var = rq[0] / 256.0 - mean*mean;
        if (var < 0.0) var = 0.0;
        double A = (double)fg0[n] / sqrt(var + 1e-5);
        AB[0] = A; AB[1] = (double)fb0[n] - mean*A;
    }
    __syncthreads();
    double t = fma((double)v, AB[0], AB[1]);
    af[(size_t)n*256 + b] = (t > 0.0) ? 1.f : ((t < 0.0) ? -1.f : 0.f);
}

// ---- fc1 partial dots (k-split) ----
__global__ __launch_bounds__(256) void k_fc1a(const float* __restrict__ af,
        const float* __restrict__ fw1, float* __restrict__ part9)
{
    __shared__ float swL[10][32];
    int ks = blockIdx.x, b = threadIdx.x;
    for (int i = b; i < 320; i += 256) {
        int j = i / 32, kk = i % 32;
        swL[j][kk] = fsign(fw1[j*1024 + ks*32 + kk]);
    }
    __syncthreads();
    float acc[10];
    #pragma unroll
    for (int j=0;j<10;j++) acc[j]=0.f;
    for (int kk = 0; kk < 32; kk++) {
        float a = af[(size_t)(ks*32+kk)*256 + b];
        #pragma unroll
        for (int j=0;j<10;j++) acc[j] += a * swL[j][kk];
    }
    #pragma unroll
    for (int j=0;j<10;j++) part9[((size_t)ks*256 + b)*10 + j] = acc[j];
}

// ---- fc1 finish: prelu, bn over batch, scale ----
__global__ __launch_bounds__(256) void k_fc1b(const float* __restrict__ part9,
        const float* __restrict__ fp1, const float* __restrict__ fg1,
        const float* __restrict__ fb1, const float* __restrict__ scale,
        float* __restrict__ out)
{
    int b = threadIdx.x;
    float v[10];
    #pragma unroll
    for (int j=0;j<10;j++) v[j]=0.f;
    for (int ks=0; ks<32; ks++)
        #pragma unroll
        for (int j=0;j<10;j++) v[j] += part9[((size_t)ks*256+b)*10 + j];
    #pragma unroll
    for (int j=0;j<10;j++){
        float a = fp1[j];
        v[j] = (v[j] >= 0.f) ? v[j] : a*v[j];
    }
    __shared__ double sv[256];
    __shared__ double AB[2][10];
    for (int j=0;j<10;j++){
        sv[b] = (double)v[j];
        __syncthreads();
        for (int off=128;off>0;off>>=1){ if(b<off) sv[b]+=sv[b+off]; __syncthreads(); }
        double mean = sv[0]/256.0;
        __syncthreads();
        double d = (double)v[j]-mean;
        sv[b] = d*d;
        __syncthreads();
        for (int off=128;off>0;off>>=1){ if(b<off) sv[b]+=sv[b+off]; __syncthreads(); }
        if (b==0){
            double var = sv[0]/256.0;
            double A = (double)fg1[j]/sqrt(var+1e-5);
            AB[0][j]=A; AB[1][j]=(double)fb1[j] - mean*A;
        }
        __syncthreads();
    }
    float sc = scale[0];
    #pragma unroll
    for (int j=0;j<10;j++)
        out[b*10+j] = (float)fma((double)v[j], AB[0][j], AB[1][j]) * sc;
}

extern "C" void kernel_launch(void* const* d_in, const int* in_sizes, int n_in,
                              void* d_out, int out_size, void* d_ws, size_t ws_size,
                              hipStream_t stream)
{
    const float* x    = (const float*)d_in[0];
    const float* cw0  = (const float*)d_in[1];
    const float* cp0  = (const float*)d_in[2];
    const float* cg0  = (const float*)d_in[3];
    const float* cb0  = (const float*)d_in[4];
    const float* cw1  = (const float*)d_in[5];
    const float* cp1  = (const float*)d_in[6];
    const float* cg1  = (const float*)d_in[7];
    const float* cb1  = (const float*)d_in[8];
    const float* fw0  = (const float*)d_in[9];
    const float* fp0  = (const float*)d_in[10];
    const float* fg0  = (const float*)d_in[11];
    const float* fb0  = (const float*)d_in[12];
    const float* fw1  = (const float*)d_in[13];
    const float* fp1  = (const float*)d_in[14];
    const float* fg1  = (const float*)d_in[15];
    const float* fb1  = (const float*)d_in[16];
    const float* scale= (const float*)d_in[17];

    char* ws = (char*)d_ws;
    size_t off = 0;
    auto alloc = [&](size_t bytes)->char* {
        char* r = ws + off; off = (off + bytes + 255) & ~(size_t)255; return r; };

    // zeroed region (contiguous, one memset)
    double*   S0    = (double*)alloc(64*8);
    double*   Q0    = (double*)alloc(64*8);
    double*   S1    = (double*)alloc(128*8);
    double*   Q1    = (double*)alloc(128*8);
    unsigned* zcnt  = (unsigned*)alloc(256);
    int*      corr  = (int*)alloc((size_t)256*1024*4);
    size_t zero_bytes = off;
    // scratch
    double*   A0B0  = (double*)alloc(128*8);
    double*   A1B1  = (double*)alloc(256*8);
    int8_t*   h0s   = (int8_t*)alloc((size_t)256*784*64);
    uint64_t* hp    = (uint64_t*)alloc((size_t)256*784*8);
    int16_t*  h1s   = (int16_t*)alloc((size_t)256*128*784*2);
    uint64_t* ap_t  = (uint64_t*)alloc((size_t)KW*256*8);
    uint64_t* wn1   = (uint64_t*)alloc(1152*8);
    uint64_t* wnz1  = (uint64_t*)alloc(1152*8);
    uint64_t* wp_t  = (uint64_t*)alloc((size_t)KW*N1*8);
    int16_t*  pcpart= (int16_t*)alloc((size_t)KS2*N1*BATCH*2);
    float*    af    = (float*)alloc((size_t)1024*256*4);
    float*    part9 = (float*)alloc((size_t)32*256*10*4);
    uint64_t* zlist = (uint64_t*)alloc((size_t)ZCAP*16);
    (void)ws_size; (void)in_sizes; (void)n_in; (void)out_size;

    hipMemsetAsync(d_ws, 0, zero_bytes, stream);
    k_conv0  <<<256,    256, 0, stream>>>(x, cw0, cp0, h0s, S0, Q0);
    k_bnfin  <<<1,       64, 0, stream>>>(S0, Q0, cg0, cb0, A0B0, 64, 1.0/200704.0);
    k_pack_h0<<<50176, 256, 0, stream>>>(h0s, cp0, A0B0, hp);
    k_pack_w1<<<288,   256, 0, stream>>>(cw1, wn1, wnz1);
    k_conv1  <<<16384, 256, 0, stream>>>(hp, wn1, wnz1, h1s);
    k_stats1 <<<1024,  256, 0, stream>>>(h1s, cp1, S1, Q1);
    k_bnfin  <<<1,     128, 0, stream>>>(S1, Q1, cg1, cb1, A1B1, 128, 1.0/200704.0);
    k_pack_a0<<<100352,256, 0, stream>>>(h1s, cp1, A1B1, ap_t);
    k_pack_w0<<<KW,    256, 0, stream>>>(fw0, wp_t, zcnt, zlist);
    k_fc0g   <<<KS2*32,256, 0, stream>>>(wp_t, ap_t, pcpart);
    k_corr   <<<64,    256, 0, stream>>>(zcnt, zlist, ap_t, corr);
    k_fc0ep  <<<1024,  256, 0, stream>>>(pcpart, corr, fp0, fg0, fb0, af);
    k_fc1a   <<<32,    256, 0, stream>>>(af, fw1, part9);
    k_fc1b   <<<1,     256, 0, stream>>>(part9, fp1, fg1, fb1, scale, (float*)d_out);
}

// Round 3
// 403.822 us; speedup vs baseline: 2.6071x; 1.0619x over previous
//
#include <hip/hip_runtime.h>
#include <stdint.h>

// ---------------------------------------------------------------------------
// Binary net:  conv0(1->64,3x3) -> prelu -> bn -> bin
//              conv1(64->128,3x3) -> prelu -> bn -> bin
//              fc0(100352->1024)  -> prelu -> bn -> bin
//              fc1(1024->10)      -> prelu -> bn -> *scale
// All inner binarize(bn(x)) collapse to sign(v*A_c + B_c).
// fc0 = stream-pack fw0 (HBM-bound) + XOR/popcount GEMM (VALU-bound).
// NOTE: no hipMemsetAsync — graph memset node measured at 243 us for 1 MB;
// we zero the tiny stats region with a one-block kernel instead.
// ---------------------------------------------------------------------------

static constexpr int BATCH = 256;
static constexpr int K0    = 100352;  // 128*784
static constexpr int KW    = 1568;    // K0/64 words
static constexpr int N1    = 1024;
// fc0 GEMM tiling
static constexpr int KS2   = 49;      // k-splits
static constexpr int JW2   = 32;      // words per split (KW/KS2)
static constexpr int SUB2  = 8;       // words per LDS subchunk
static constexpr int NS2   = 4;       // JW2/SUB2
static constexpr unsigned ZCAP = 65536;

__device__ __forceinline__ float fsign(float v){
    return (v > 0.f) ? 1.f : ((v < 0.f) ? -1.f : 0.f);
}

// ---- zero the stats/zcnt region (replaces pathological graph memset) ----
__global__ void k_zero(int* __restrict__ p)
{
    p[threadIdx.x] = 0;   // 1024 ints = 4096 B covers S0,Q0,S1,Q1,zcnt
}

// ---- conv block 0: sign(x) conv3x3 sign(cw0), prelu, accumulate bn stats ----
__global__ __launch_bounds__(256) void k_conv0(const float* __restrict__ x,
        const float* __restrict__ cw0, const float* __restrict__ cp0,
        int8_t* __restrict__ h0s, double* __restrict__ S0, double* __restrict__ Q0)
{
    __shared__ float img[30][30];
    __shared__ float redS[4][64];
    __shared__ float redQ[4][64];
    int b = blockIdx.x;
    int tid = threadIdx.x;
    for (int i = tid; i < 900; i += 256) ((float*)img)[i] = 0.f;
    __syncthreads();
    for (int i = tid; i < 784; i += 256) {
        float v = x[b*784 + i];
        img[1 + i/28][1 + i%28] = fsign(v);
    }
    __syncthreads();
    int lane = tid & 63, wv = tid >> 6;   // lane = out channel
    float wsg[9];
    #pragma unroll
    for (int t = 0; t < 9; t++) wsg[t] = fsign(cw0[lane*9 + t]);
    float a = cp0[lane];
    float accS = 0.f, accQ = 0.f;
    for (int i = 0; i < 196; i++) {
        int p = wv*196 + i;
        int y = p / 28, xx = p % 28;
        float s = 0.f;
        #pragma unroll
        for (int dy = 0; dy < 3; dy++)
            #pragma unroll
            for (int dx = 0; dx < 3; dx++)
                s += img[y+dy][xx+dx] * wsg[dy*3+dx];
        h0s[(size_t)(b*784 + p)*64 + lane] = (int8_t)(int)s;
        float v = (s >= 0.f) ? s : a*s;
        accS += v; accQ += v*v;
    }
    redS[wv][lane] = accS; redQ[wv][lane] = accQ;
    __syncthreads();
    if (tid < 64) {
        double s = (double)redS[0][tid] + redS[1][tid] + redS[2][tid] + redS[3][tid];
        double q = (double)redQ[0][tid] + redQ[1][tid] + redQ[2][tid] + redQ[3][tid];
        atomicAdd(&S0[tid], s);
        atomicAdd(&Q0[tid], q);
    }
}

// ---- finalize bn -> affine threshold coefficients (A,B) in f64 ----
__global__ void k_bnfin(const double* __restrict__ S, const double* __restrict__ Q,
        const float* __restrict__ g, const float* __restrict__ bb,
        double* __restrict__ AB, int C, double invN)
{
    int c = threadIdx.x;
    if (c >= C) return;
    double mean = S[c] * invN;
    double var  = Q[c] * invN - mean*mean;
    if (var < 0.0) var = 0.0;
    double A = (double)g[c] / sqrt(var + 1e-5);
    AB[c]     = A;
    AB[C + c] = (double)bb[c] - mean*A;
}

// ---- pack conv1 input: one u64 per pixel (bit c = negative) ----
__global__ __launch_bounds__(256) void k_pack_h0(const int8_t* __restrict__ h0s,
        const float* __restrict__ cp0, const double* __restrict__ AB,
        uint64_t* __restrict__ hp)
{
    int idx = blockIdx.x * 4 + (threadIdx.x >> 6);   // = b*784+p
    int lane = threadIdx.x & 63;
    float s = (float)h0s[(size_t)idx*64 + lane];
    float a = cp0[lane];
    float v = (s >= 0.f) ? s : a*s;
    double t = fma((double)v, AB[lane], AB[64 + lane]);
    uint64_t m = __ballot(t < 0.0);
    if (lane == 0) hp[idx] = m;
}

// ---- pack conv1 weights: neg mask + nonzero mask per (oc, tap) ----
__global__ __launch_bounds__(256) void k_pack_w1(const float* __restrict__ cw1,
        uint64_t* __restrict__ wn1, uint64_t* __restrict__ wnz1)
{
    int idx = blockIdx.x*4 + (threadIdx.x >> 6);     // (oc*9 + t)
    int lane = threadIdx.x & 63;                     // lane = in channel
    int oc = idx / 9, t = idx % 9;
    float w = cw1[oc*576 + lane*9 + t];
    uint64_t n = __ballot(w < 0.f);
    uint64_t z = __ballot(w != 0.f);
    if (lane == 0) { wn1[idx] = n; wnz1[idx] = z; }
}

// ---- conv1 via XOR/popcount + fused bn1 statistics ----
__global__ __launch_bounds__(256) void k_conv1(const uint64_t* __restrict__ hp,
        const uint64_t* __restrict__ wn1, const uint64_t* __restrict__ wnz1,
        const float* __restrict__ cp1, int16_t* __restrict__ h1s,
        double* __restrict__ S1, double* __restrict__ Q1)
{
    __shared__ float lS[4][8];
    __shared__ float lQ[4][8];
    int bid = blockIdx.x;
    int ocg = bid & 15;
    int ptg = (bid >> 4) & 3;
    int b   = bid >> 6;
    int wv = threadIdx.x >> 6, lane = threadIdx.x & 63;
    int pt = ptg*4 + wv;
    bool active = (pt < 13);
    int p = active ? (pt*64 + lane) : 0;
    bool pvalid = active && (p < 784);
    int y = p / 28, xx = p % 28;
    uint64_t nb[9]; unsigned vmask = 0;
    #pragma unroll
    for (int dy = 0; dy < 3; dy++)
        #pragma unroll
        for (int dx = 0; dx < 3; dx++) {
            int t = dy*3+dx;
            int yy = y + dy - 1, xv = xx + dx - 1;
            bool ok = (yy >= 0 && yy < 28 && xv >= 0 && xv < 28);
            nb[t] = hp[b*784 + (ok ? (yy*28+xv) : 0)];
            if (ok) vmask |= 1u << t;
        }
    #pragma unroll
    for (int o = 0; o < 8; o++) {
        int oc = ocg*8 + o;
        int base = oc*9;
        int acc = 0;
        #pragma unroll
        for (int t = 0; t < 9; t++) {
            uint64_t wn = wn1[base+t], wz = wnz1[base+t];
            if (vmask & (1u<<t))
                acc += (int)__popcll(wz) - 2*(int)__popcll((nb[t] ^ wn) & wz);
        }
        if (pvalid) h1s[((size_t)b*128 + oc)*784 + p] = (int16_t)acc;
        float pr = cp1[oc];
        float v = pvalid ? ((acc >= 0) ? (float)acc : pr*(float)acc) : 0.f;
        float s = v, q = v*v;
        #pragma unroll
        for (int off = 32; off; off >>= 1) {
            s += __shfl_xor(s, off);
            q += __shfl_xor(q, off);
        }
        if (lane == 0) { lS[wv][o] = s; lQ[wv][o] = q; }
    }
    __syncthreads();
    if (threadIdx.x < 8) {
        int o = threadIdx.x;
        double s = (double)lS[0][o] + lS[1][o] + lS[2][o] + lS[3][o];
        double q = (double)lQ[0][o] + lQ[1][o] + lQ[2][o] + lQ[3][o];
        atomicAdd(&S1[ocg*8 + o], s);
        atomicAdd(&Q1[ocg*8 + o], q);
    }
}

// ---- pack fc0 activations, transposed: ap_t[word j][batch b] ----
__global__ __launch_bounds__(256) void k_pack_a0(const int16_t* __restrict__ h1s,
        const float* __restrict__ cp1, const double* __restrict__ AB,
        uint64_t* __restrict__ ap_t)
{
    int bb = blockIdx.x / 392;
    int jg = blockIdx.x % 392;
    int j = jg*4 + (threadIdx.x >> 6);
    int lane = threadIdx.x & 63;
    int k = j*64 + lane;                  // k = oc*784 + p (flatten order)
    int oc = k / 784;
    int p  = k - oc*784;
    float s = (float)h1s[((size_t)bb*128 + oc)*784 + p];
    float a = cp1[oc];
    float v = (s >= 0.f) ? s : a*s;
    double t = fma((double)v, AB[oc], AB[128+oc]);
    uint64_t m = __ballot(t < 0.0);
    if (lane == 0) ap_t[(size_t)j*256 + bb] = m;
}

// ---- pack fc0 weights: 8 rows/block, sequential reads, 64B coalesced writes ----
__global__ __launch_bounds__(256) void k_pack_w0(const float* __restrict__ fw0,
        uint64_t* __restrict__ wp_t, unsigned* __restrict__ zcnt,
        uint64_t* __restrict__ zlist)
{
    int ng = blockIdx.x >> 3;        // 0..127 n-group (8 rows each)
    int ch = blockIdx.x & 7;         // 0..7 jw chunk
    int wv = threadIdx.x >> 6, lane = threadIdx.x & 63;
    int n0 = ng*8;
    int jw0 = ch*196 + wv*49;
    const float* base = fw0 + (size_t)n0*K0 + lane;
    for (int t = 0; t < 49; ++t) {
        int jw = jw0 + t;
        size_t koff = (size_t)jw*64;
        uint64_t nb[8], zb[8];
        #pragma unroll
        for (int r = 0; r < 8; ++r) {
            float w = base[(size_t)r*K0 + koff];
            nb[r] = __ballot(w < 0.f);
            zb[r] = __ballot(w == 0.f);
        }
        uint64_t mine = nb[0];
        #pragma unroll
        for (int r = 1; r < 8; ++r) mine = (lane == r) ? nb[r] : mine;
        if (lane < 8) wp_t[(size_t)jw*N1 + n0 + lane] = mine;
        if (lane == 0) {
            #pragma unroll
            for (int r = 0; r < 8; ++r) if (zb[r]) {
                unsigned id = atomicAdd(zcnt, 1u);
                if (id < ZCAP) {
                    zlist[2*id]   = ((uint64_t)(unsigned)(n0+r) << 32) | (unsigned)jw;
                    zlist[2*id+1] = zb[r];
                }
            }
        }
    }
}

// ---- fc0 XOR/popcount GEMM on packed operands ----
__global__ __launch_bounds__(256) void k_fc0g(const uint64_t* __restrict__ wp_t,
        const uint64_t* __restrict__ ap_t, int16_t* __restrict__ pcpart)
{
    __shared__ uint64_t wL[SUB2][32];
    __shared__ uint64_t apL[SUB2][256];
    int nt = blockIdx.x & 31;     // 32 n-tiles of 32
    int ks = blockIdx.x >> 5;     // 49 k-splits
    int tid = threadIdx.x;
    int bq = tid & 31;            // b = bq + 32*i
    int nq = tid >> 5;            // n = n0 + nq + 8*k
    int n0 = nt*32;
    int pc[8][4];
    #pragma unroll
    for (int i=0;i<8;i++)
        #pragma unroll
        for (int k=0;k<4;k++) pc[i][k]=0;
    int jbase = ks*JW2;
    for (int c = 0; c < NS2; c++) {
        int j0 = jbase + c*SUB2;
        #pragma unroll
        for (int r = 0; r < SUB2; r++)
            apL[r][tid] = ap_t[(size_t)(j0 + r)*256 + tid];
        {
            int jj = tid >> 5, n = tid & 31;
            wL[jj][n] = wp_t[(size_t)(j0 + jj)*N1 + n0 + n];
        }
        __syncthreads();
        #pragma unroll
        for (int jj = 0; jj < SUB2; jj++) {
            uint64_t aw[8], ww[4];
            #pragma unroll
            for (int i = 0; i < 8; i++) aw[i] = apL[jj][bq + 32*i];
            #pragma unroll
            for (int k = 0; k < 4; k++) ww[k] = wL[jj][nq + 8*k];
            #pragma unroll
            for (int i = 0; i < 8; i++)
                #pragma unroll
                for (int k = 0; k < 4; k++)
                    pc[i][k] += (int)__popcll(aw[i] ^ ww[k]);
        }
        __syncthreads();
    }
    #pragma unroll
    for (int k = 0; k < 4; k++) {
        int n = n0 + nq + 8*k;
        #pragma unroll
        for (int i = 0; i < 8; i++)
            pcpart[((size_t)ks*N1 + n)*BATCH + (bq + 32*i)] = (int16_t)pc[i][k];
    }
}

// ---- fc0 epilogue: combine partials + zero-weight corrections, bn, binarize ----
__global__ __launch_bounds__(256) void k_fc0ep(const int16_t* __restrict__ pcpart,
        const unsigned* __restrict__ zcnt, const uint64_t* __restrict__ zlist,
        const uint64_t* __restrict__ ap_t, const float* __restrict__ fp0,
        const float* __restrict__ fg0, const float* __restrict__ fb0,
        float* __restrict__ af)
{
    int n = blockIdx.x, b = threadIdx.x;
    int pc = 0;
    #pragma unroll
    for (int ks = 0; ks < KS2; ks++) pc += (int)pcpart[((size_t)ks*N1 + n)*BATCH + b];
    int s = K0 - 2*pc;
    unsigned cnt = *zcnt; if (cnt > ZCAP) cnt = ZCAP;
    for (unsigned e = 0; e < cnt; ++e) {       // essentially never taken
        uint64_t key = zlist[2*e];
        if ((int)(key >> 32) == n) {
            uint64_t zm = zlist[2*e+1];
            uint64_t a = ap_t[(size_t)(key & 0xffffffffu)*256 + b];
            s += 2*(int)__popcll(a & zm) - (int)__popcll(zm);
        }
    }
    float a = fp0[n];
    float v = (s >= 0) ? (float)s : a*(float)s;
    __shared__ double rs[256], rq[256];
    rs[b] = v; rq[b] = (double)v*(double)v;
    __syncthreads();
    for (int off=128; off>0; off>>=1){
        if (b<off){ rs[b]+=rs[b+off]; rq[b]+=rq[b+off]; }
        __syncthreads();
    }
    __shared__ double AB[2];
    if (b == 0) {
        double mean = rs[0] / 256.0;
        double var = rq[0] / 256.0 - mean*mean;
        if (var < 0.0) var = 0.0;
        double A = (double)fg0[n] / sqrt(var + 1e-5);
        AB[0] = A; AB[1] = (double)fb0[n] - mean*A;
    }
    __syncthreads();
    double t = fma((double)v, AB[0], AB[1]);
    af[(size_t)n*256 + b] = (t > 0.0) ? 1.f : ((t < 0.0) ? -1.f : 0.f);
}

// ---- fc1 partial dots (k-split) ----
__global__ __launch_bounds__(256) void k_fc1a(const float* __restrict__ af,
        const float* __restrict__ fw1, float* __restrict__ part9)
{
    __shared__ float swL[10][32];
    int ks = blockIdx.x, b = threadIdx.x;
    for (int i = b; i < 320; i += 256) {
        int j = i / 32, kk = i % 32;
        swL[j][kk] = fsign(fw1[j*1024 + ks*32 + kk]);
    }
    __syncthreads();
    float acc[10];
    #pragma unroll
    for (int j=0;j<10;j++) acc[j]=0.f;
    for (int kk = 0; kk < 32; kk++) {
        float a = af[(size_t)(ks*32+kk)*256 + b];
        #pragma unroll
        for (int j=0;j<10;j++) acc[j] += a * swL[j][kk];
    }
    #pragma unroll
    for (int j=0;j<10;j++) part9[((size_t)ks*256 + b)*10 + j] = acc[j];
}

// ---- fc1 finish: prelu, bn over batch, scale ----
__global__ __launch_bounds__(256) void k_fc1b(const float* __restrict__ part9,
        const float* __restrict__ fp1, const float* __restrict__ fg1,
        const float* __restrict__ fb1, const float* __restrict__ scale,
        float* __restrict__ out)
{
    int b = threadIdx.x;
    float v[10];
    #pragma unroll
    for (int j=0;j<10;j++) v[j]=0.f;
    for (int ks=0; ks<32; ks++)
        #pragma unroll
        for (int j=0;j<10;j++) v[j] += part9[((size_t)ks*256+b)*10 + j];
    #pragma unroll
    for (int j=0;j<10;j++){
        float a = fp1[j];
        v[j] = (v[j] >= 0.f) ? v[j] : a*v[j];
    }
    __shared__ double sv[256];
    __shared__ double AB[2][10];
    for (int j=0;j<10;j++){
        sv[b] = (double)v[j];
        __syncthreads();
        for (int off=128;off>0;off>>=1){ if(b<off) sv[b]+=sv[b+off]; __syncthreads(); }
        double mean = sv[0]/256.0;
        __syncthreads();
        double d = (double)v[j]-mean;
        sv[b] = d*d;
        __syncthreads();
        for (int off=128;off>0;off>>=1){ if(b<off) sv[b]+=sv[b+off]; __syncthreads(); }
        if (b==0){
            double var = sv[0]/256.0;
            double A = (double)fg1[j]/sqrt(var+1e-5);
            AB[0][j]=A; AB[1][j]=(double)fb1[j] - mean*A;
        }
        __syncthreads();
    }
    float sc = scale[0];
    #pragma unroll
    for (int j=0;j<10;j++)
        out[b*10+j] = (float)fma((double)v[j], AB[0][j], AB[1][j]) * sc;
}

extern "C" void kernel_launch(void* const* d_in, const int* in_sizes, int n_in,
                              void* d_out, int out_size, void* d_ws, size_t ws_size,
                              hipStream_t stream)
{
    const float* x    = (const float*)d_in[0];
    const float* cw0  = (const float*)d_in[1];
    const float* cp0  = (const float*)d_in[2];
    const float* cg0  = (const float*)d_in[3];
    const float* cb0  = (const float*)d_in[4];
    const float* cw1  = (const float*)d_in[5];
    const float* cp1  = (const float*)d_in[6];
    const float* cg1  = (const float*)d_in[7];
    const float* cb1  = (const float*)d_in[8];
    const float* fw0  = (const float*)d_in[9];
    const float* fp0  = (const float*)d_in[10];
    const float* fg0  = (const float*)d_in[11];
    const float* fb0  = (const float*)d_in[12];
    const float* fw1  = (const float*)d_in[13];
    const float* fp1  = (const float*)d_in[14];
    const float* fg1  = (const float*)d_in[15];
    const float* fb1  = (const float*)d_in[16];
    const float* scale= (const float*)d_in[17];

    char* ws = (char*)d_ws;
    size_t off = 0;
    auto alloc = [&](size_t bytes)->char* {
        char* r = ws + off; off = (off + bytes + 255) & ~(size_t)255; return r; };

    // zeroed-by-k_zero region (must stay within first 4096 bytes)
    double*   S0    = (double*)alloc(64*8);
    double*   Q0    = (double*)alloc(64*8);
    double*   S1    = (double*)alloc(128*8);
    double*   Q1    = (double*)alloc(128*8);
    unsigned* zcnt  = (unsigned*)alloc(256);
    // scratch (fully overwritten each call before use)
    double*   A0B0  = (double*)alloc(128*8);
    double*   A1B1  = (double*)alloc(256*8);
    int8_t*   h0s   = (int8_t*)alloc((size_t)256*784*64);
    uint64_t* hp    = (uint64_t*)alloc((size_t)256*784*8);
    int16_t*  h1s   = (int16_t*)alloc((size_t)256*128*784*2);
    uint64_t* ap_t  = (uint64_t*)alloc((size_t)KW*256*8);
    uint64_t* wn1   = (uint64_t*)alloc(1152*8);
    uint64_t* wnz1  = (uint64_t*)alloc(1152*8);
    uint64_t* wp_t  = (uint64_t*)alloc((size_t)KW*N1*8);
    int16_t*  pcpart= (int16_t*)alloc((size_t)KS2*N1*BATCH*2);
    float*    af    = (float*)alloc((size_t)1024*256*4);
    float*    part9 = (float*)alloc((size_t)32*256*10*4);
    uint64_t* zlist = (uint64_t*)alloc((size_t)ZCAP*16);
    (void)ws_size; (void)in_sizes; (void)n_in; (void)out_size;

    k_zero   <<<1,    1024, 0, stream>>>((int*)d_ws);
    k_conv0  <<<256,   256, 0, stream>>>(x, cw0, cp0, h0s, S0, Q0);
    k_bnfin  <<<1,      64, 0, stream>>>(S0, Q0, cg0, cb0, A0B0, 64, 1.0/200704.0);
    k_pack_h0<<<50176, 256, 0, stream>>>(h0s, cp0, A0B0, hp);
    k_pack_w1<<<288,   256, 0, stream>>>(cw1, wn1, wnz1);
    k_conv1  <<<16384, 256, 0, stream>>>(hp, wn1, wnz1, cp1, h1s, S1, Q1);
    k_bnfin  <<<1,     128, 0, stream>>>(S1, Q1, cg1, cb1, A1B1, 128, 1.0/200704.0);
    k_pack_a0<<<100352,256, 0, stream>>>(h1s, cp1, A1B1, ap_t);
    k_pack_w0<<<1024,  256, 0, stream>>>(fw0, wp_t, zcnt, zlist);
    k_fc0g   <<<KS2*32,256, 0, stream>>>(wp_t, ap_t, pcpart);
    k_fc0ep  <<<1024,  256, 0, stream>>>(pcpart, zcnt, zlist, ap_t, fp0, fg0, fb0, af);
    k_fc1a   <<<32,    256, 0, stream>>>(af, fw1, part9);
    k_fc1b   <<<1,     256, 0, stream>>>(part9, fp1, fg1, fb1, scale, (float*)d_out);
}

// Round 4
// 355.055 us; speedup vs baseline: 2.9652x; 1.1374x over previous
//
#include <hip/hip_runtime.h>
#include <stdint.h>

// ---------------------------------------------------------------------------
// Binary net:  conv0(1->64,3x3) -> prelu -> bn -> bin
//              conv1(64->128,3x3) -> prelu -> bn -> bin
//              fc0(100352->1024)  -> prelu -> bn -> bin
//              fc1(1024->10)      -> prelu -> bn -> *scale
// binarize(bn(x)) == sign(v*A_c + B_c)  (A,B from batch stats, f64).
// fc0: stream-pack fw0 sequentially per wave (interleaved bit order:
// word j=4q+c holds elements k=256q+4i+c at bit i; popcount(x^y) is
// invariant under any common bit permutation, so GEMM logic unchanged,
// provided activations use the SAME packing -- they do).
// ---------------------------------------------------------------------------

static constexpr int BATCH = 256;
static constexpr int K0    = 100352;  // 128*784
static constexpr int KW    = 1568;    // K0/64 words
static constexpr int N1    = 1024;
static constexpr int KS2   = 49;      // k-splits
static constexpr int JW2   = 32;      // words per split (KW/KS2)
static constexpr int SUB2  = 8;       // ap words per LDS subchunk
static constexpr int NS2   = 4;       // JW2/SUB2
static constexpr unsigned ZCAP = 65536;

__device__ __forceinline__ float fsign(float v){
    return (v > 0.f) ? 1.f : ((v < 0.f) ? -1.f : 0.f);
}

// ---- pack conv1 weights + zero the stats/zcnt region (block 0) ----
__global__ __launch_bounds__(256) void k_pack_w1(const float* __restrict__ cw1,
        uint64_t* __restrict__ wn1, uint64_t* __restrict__ wnz1,
        int* __restrict__ zero_region)
{
    if (blockIdx.x == 0) {
        for (int i = threadIdx.x; i < 832; i += 256) zero_region[i] = 0;
    }
    int idx = blockIdx.x*4 + (threadIdx.x >> 6);     // (oc*9 + t)
    int lane = threadIdx.x & 63;                     // lane = in channel
    int oc = idx / 9, t = idx % 9;
    float w = cw1[oc*576 + lane*9 + t];
    uint64_t n = __ballot(w < 0.f);
    uint64_t z = __ballot(w != 0.f);
    if (lane == 0) { wn1[idx] = n; wnz1[idx] = z; }
}

// ---- conv block 0: sign(x) conv3x3 sign(cw0), prelu, accumulate bn stats ----
__global__ __launch_bounds__(256) void k_conv0(const float* __restrict__ x,
        const float* __restrict__ cw0, const float* __restrict__ cp0,
        int8_t* __restrict__ h0s, double* __restrict__ S0, double* __restrict__ Q0)
{
    __shared__ float img[30][30];
    __shared__ float redS[4][64];
    __shared__ float redQ[4][64];
    int b = blockIdx.x;
    int tid = threadIdx.x;
    for (int i = tid; i < 900; i += 256) ((float*)img)[i] = 0.f;
    __syncthreads();
    for (int i = tid; i < 784; i += 256) {
        float v = x[b*784 + i];
        img[1 + i/28][1 + i%28] = fsign(v);
    }
    __syncthreads();
    int lane = tid & 63, wv = tid >> 6;   // lane = out channel
    float wsg[9];
    #pragma unroll
    for (int t = 0; t < 9; t++) wsg[t] = fsign(cw0[lane*9 + t]);
    float a = cp0[lane];
    float accS = 0.f, accQ = 0.f;
    for (int i = 0; i < 196; i++) {
        int p = wv*196 + i;
        int y = p / 28, xx = p % 28;
        float s = 0.f;
        #pragma unroll
        for (int dy = 0; dy < 3; dy++)
            #pragma unroll
            for (int dx = 0; dx < 3; dx++)
                s += img[y+dy][xx+dx] * wsg[dy*3+dx];
        h0s[(size_t)(b*784 + p)*64 + lane] = (int8_t)(int)s;  // exact small int
        float v = (s >= 0.f) ? s : a*s;
        accS += v; accQ += v*v;
    }
    redS[wv][lane] = accS; redQ[wv][lane] = accQ;
    __syncthreads();
    if (tid < 64) {
        double s = (double)redS[0][tid] + redS[1][tid] + redS[2][tid] + redS[3][tid];
        double q = (double)redQ[0][tid] + redQ[1][tid] + redQ[2][tid] + redQ[3][tid];
        atomicAdd(&S0[tid], s);
        atomicAdd(&Q0[tid], q);
    }
}

// ---- bn0 finalize -> 19-entry sign LUT per channel (conv0 sums in [-9,9]) ----
__global__ void k_bnfin0(const double* __restrict__ S, const double* __restrict__ Q,
        const float* __restrict__ g, const float* __restrict__ bb,
        const float* __restrict__ cp0, unsigned* __restrict__ lut)
{
    int c = threadIdx.x;   // 64
    double mean = S[c] * (1.0/200704.0);
    double var  = Q[c] * (1.0/200704.0) - mean*mean;
    if (var < 0.0) var = 0.0;
    double A = (double)g[c] / sqrt(var + 1e-5);
    double B = (double)bb[c] - mean*A;
    float a = cp0[c];
    unsigned m = 0;
    for (int s = -9; s <= 9; ++s) {
        float v = (s >= 0) ? (float)s : a*(float)s;   // same f32 path as before
        double t = fma((double)v, A, B);
        if (t < 0.0) m |= 1u << (s + 9);
    }
    lut[c] = m;
}

// ---- bn1 finalize -> affine threshold coefficients (A,B) in f64 ----
__global__ void k_bnfin(const double* __restrict__ S, const double* __restrict__ Q,
        const float* __restrict__ g, const float* __restrict__ bb,
        double* __restrict__ AB, int C, double invN)
{
    int c = threadIdx.x;
    if (c >= C) return;
    double mean = S[c] * invN;
    double var  = Q[c] * invN - mean*mean;
    if (var < 0.0) var = 0.0;
    double A = (double)g[c] / sqrt(var + 1e-5);
    AB[c]     = A;
    AB[C + c] = (double)bb[c] - mean*A;
}

// ---- pack conv1 input: one thread per pixel, 64B vector load + LUT ----
__global__ __launch_bounds__(256) void k_pack_h0(const int8_t* __restrict__ h0s,
        const unsigned* __restrict__ lut, uint64_t* __restrict__ hp)
{
    __shared__ unsigned l[64];
    int tid = threadIdx.x;
    if (tid < 64) l[tid] = lut[tid];
    __syncthreads();
    int pixel = blockIdx.x*256 + tid;      // grid 784*256 == 200704 exact
    const int4* p4 = (const int4*)(h0s + (size_t)pixel*64);
    int4 va = p4[0], vb = p4[1], vc = p4[2], vd = p4[3];
    int wa[16] = {va.x,va.y,va.z,va.w, vb.x,vb.y,vb.z,vb.w,
                  vc.x,vc.y,vc.z,vc.w, vd.x,vd.y,vd.z,vd.w};
    unsigned lo = 0, hi = 0;
    #pragma unroll
    for (int wi = 0; wi < 16; ++wi) {
        unsigned w = (unsigned)wa[wi];
        #pragma unroll
        for (int c2 = 0; c2 < 4; ++c2) {
            int ch = wi*4 + c2;
            int s = (int)(signed char)(w >> (8*c2));
            unsigned bit = (l[ch] >> (s + 9)) & 1u;
            if (ch < 32) lo |= bit << ch; else hi |= bit << (ch - 32);
        }
    }
    hp[pixel] = ((uint64_t)hi << 32) | lo;
}

// ---- conv1 via XOR/popcount + fused bn1 statistics ----
__global__ __launch_bounds__(256) void k_conv1(const uint64_t* __restrict__ hp,
        const uint64_t* __restrict__ wn1, const uint64_t* __restrict__ wnz1,
        const float* __restrict__ cp1, int16_t* __restrict__ h1s,
        double* __restrict__ S1, double* __restrict__ Q1)
{
    __shared__ float lS[4][8];
    __shared__ float lQ[4][8];
    int bid = blockIdx.x;
    int ocg = bid & 15;
    int ptg = (bid >> 4) & 3;
    int b   = bid >> 6;
    int wv = threadIdx.x >> 6, lane = threadIdx.x & 63;
    int pt = ptg*4 + wv;
    bool active = (pt < 13);
    int p = active ? (pt*64 + lane) : 0;
    bool pvalid = active && (p < 784);
    int y = p / 28, xx = p % 28;
    uint64_t nb[9]; unsigned vmask = 0;
    #pragma unroll
    for (int dy = 0; dy < 3; dy++)
        #pragma unroll
        for (int dx = 0; dx < 3; dx++) {
            int t = dy*3+dx;
            int yy = y + dy - 1, xv = xx + dx - 1;
            bool ok = (yy >= 0 && yy < 28 && xv >= 0 && xv < 28);
            nb[t] = hp[b*784 + (ok ? (yy*28+xv) : 0)];
            if (ok) vmask |= 1u << t;
        }
    #pragma unroll
    for (int o = 0; o < 8; o++) {
        int oc = ocg*8 + o;
        int base = oc*9;
        int acc = 0;
        #pragma unroll
        for (int t = 0; t < 9; t++) {
            uint64_t wn = wn1[base+t], wz = wnz1[base+t];
            if (vmask & (1u<<t))
                acc += (int)__popcll(wz) - 2*(int)__popcll((nb[t] ^ wn) & wz);
        }
        if (pvalid) h1s[((size_t)b*128 + oc)*784 + p] = (int16_t)acc;
        float pr = cp1[oc];
        float v = pvalid ? ((acc >= 0) ? (float)acc : pr*(float)acc) : 0.f;
        float s = v, q = v*v;
        #pragma unroll
        for (int off = 32; off; off >>= 1) {
            s += __shfl_xor(s, off);
            q += __shfl_xor(q, off);
        }
        if (lane == 0) { lS[wv][o] = s; lQ[wv][o] = q; }
    }
    __syncthreads();
    if (threadIdx.x < 8) {
        int o = threadIdx.x;
        double s = (double)lS[0][o] + lS[1][o] + lS[2][o] + lS[3][o];
        double q = (double)lQ[0][o] + lQ[1][o] + lQ[2][o] + lQ[3][o];
        atomicAdd(&S1[ocg*8 + o], s);
        atomicAdd(&Q1[ocg*8 + o], q);
    }
}

// ---- pack fc0 activations, interleaved order, ap_t[word j][batch b] ----
// word j = 4q+c, bit i = element k = 256q + 4i + c  (short4 per lane)
__global__ __launch_bounds__(256) void k_pack_a0(const int16_t* __restrict__ h1s,
        const float* __restrict__ cp1, const double* __restrict__ AB,
        uint64_t* __restrict__ ap_t)
{
    int blk = blockIdx.x;                 // 256*98 blocks
    int b  = blk / 98;
    int qg = blk % 98;
    int wv = threadIdx.x >> 6, lane = threadIdx.x & 63;
    int q  = qg*4 + wv;                   // 0..391
    int k0 = q*256 + lane*4;
    short4 sv = *(const short4*)(h1s + (size_t)b*K0 + k0);
    int oc = k0 / 784;                    // all 4 elements share oc (4 | 784)
    double A = AB[oc], B = AB[128 + oc];
    float a = cp1[oc];
    int ss[4] = {sv.x, sv.y, sv.z, sv.w};
    uint64_t words[4];
    #pragma unroll
    for (int c = 0; c < 4; ++c) {
        float s = (float)ss[c];
        float v = (s >= 0.f) ? s : a*s;
        double t = fma((double)v, A, B);
        words[c] = __ballot(t < 0.0);
    }
    if (lane == 0) {
        #pragma unroll
        for (int c = 0; c < 4; ++c)
            ap_t[(size_t)(4*q + c)*256 + b] = words[c];
    }
}

// ---- pack fc0 weights: fully sequential stream, wp[n][j] row-major ----
__global__ __launch_bounds__(256) void k_pack_w0(const float* __restrict__ fw0,
        uint64_t* __restrict__ wp, unsigned* __restrict__ zcnt,
        uint64_t* __restrict__ zlist)
{
    int n   = blockIdx.x >> 1;                      // 0..1023
    int oct = (blockIdx.x & 1)*4 + (threadIdx.x >> 6);  // 0..7 (49-chunk span)
    int lane = threadIdx.x & 63;
    const float* src = fw0 + (size_t)n*K0 + (size_t)oct*49*256 + lane*4;
    uint64_t* dst = wp + (size_t)n*KW + (size_t)oct*49*4;
    for (int t = 0; t < 49; ++t) {
        float4 w = *(const float4*)(src + t*256);
        uint64_t g0 = __ballot(w.x < 0.f);
        uint64_t g1 = __ballot(w.y < 0.f);
        uint64_t g2 = __ballot(w.z < 0.f);
        uint64_t g3 = __ballot(w.w < 0.f);
        uint64_t z0 = __ballot(w.x == 0.f);
        uint64_t z1 = __ballot(w.y == 0.f);
        uint64_t z2 = __ballot(w.z == 0.f);
        uint64_t z3 = __ballot(w.w == 0.f);
        if (lane == 0) {
            ulonglong2 lo{g0, g1}, hi{g2, g3};
            *(ulonglong2*)(dst + t*4)     = lo;
            *(ulonglong2*)(dst + t*4 + 2) = hi;
            uint64_t zz[4] = {z0, z1, z2, z3};
            #pragma unroll
            for (int c = 0; c < 4; ++c) if (zz[c]) {
                unsigned id = atomicAdd(zcnt, 1u);
                if (id < ZCAP) {
                    unsigned j = (unsigned)((oct*49 + t)*4 + c);
                    zlist[2*id]   = ((uint64_t)(unsigned)n << 32) | j;
                    zlist[2*id+1] = zz[c];
                }
            }
        }
    }
}

// ---- fc0 XOR/popcount GEMM: 32x32 weight tile in LDS + ap subchunks ----
__global__ __launch_bounds__(256) void k_fc0g(const uint64_t* __restrict__ wp,
        const uint64_t* __restrict__ ap_t, int16_t* __restrict__ pcpart)
{
    __shared__ uint64_t wT[32][33];       // +1 pad: kills 8-way bank conflict
    __shared__ uint64_t apL[SUB2][256];
    int nt = blockIdx.x & 31;
    int ks = blockIdx.x >> 5;
    int tid = threadIdx.x;
    int bq = tid & 31;            // b = bq + 32*i
    int nq = tid >> 5;            // n = n0 + nq + 8*k
    int n0 = nt*32, j0 = ks*JW2;
    {   // load 32 rows x 32 words (8KB), 256B contiguous per row
        int row = tid >> 3;               // 0..31
        int wo  = (tid & 7) * 4;          // 0..28
        const uint64_t* src = wp + (size_t)(n0 + row)*KW + j0 + wo;
        ulonglong2 v0 = *(const ulonglong2*)(src);
        ulonglong2 v1 = *(const ulonglong2*)(src + 2);
        wT[row][wo+0] = v0.x; wT[row][wo+1] = v0.y;
        wT[row][wo+2] = v1.x; wT[row][wo+3] = v1.y;
    }
    int pc[8][4];
    #pragma unroll
    for (int i = 0; i < 8; i++)
        #pragma unroll
        for (int k = 0; k < 4; k++) pc[i][k] = 0;
    for (int c = 0; c < NS2; c++) {
        #pragma unroll
        for (int r = 0; r < SUB2; r++)
            apL[r][tid] = ap_t[(size_t)(j0 + c*SUB2 + r)*256 + tid];
        __syncthreads();                  // also covers wT on first pass
        #pragma unroll
        for (int jj = 0; jj < SUB2; jj++) {
            uint64_t aw[8], ww[4];
            #pragma unroll
            for (int i = 0; i < 8; i++) aw[i] = apL[jj][bq + 32*i];
            #pragma unroll
            for (int k = 0; k < 4; k++) ww[k] = wT[nq + 8*k][c*8 + jj];
            #pragma unroll
            for (int i = 0; i < 8; i++)
                #pragma unroll
                for (int k = 0; k < 4; k++)
                    pc[i][k] += (int)__popcll(aw[i] ^ ww[k]);
        }
        __syncthreads();
    }
    #pragma unroll
    for (int k = 0; k < 4; k++) {
        int n = n0 + nq + 8*k;
        #pragma unroll
        for (int i = 0; i < 8; i++)
            pcpart[((size_t)ks*N1 + n)*BATCH + (bq + 32*i)] = (int16_t)pc[i][k];
    }
}

// ---- fc0 epilogue: combine partials + zero-weight corrections, bn, binarize ----
__global__ __launch_bounds__(256) void k_fc0ep(const int16_t* __restrict__ pcpart,
        const unsigned* __restrict__ zcnt, const uint64_t* __restrict__ zlist,
        const uint64_t* __restrict__ ap_t, const float* __restrict__ fp0,
        const float* __restrict__ fg0, const float* __restrict__ fb0,
        float* __restrict__ af)
{
    int n = blockIdx.x, b = threadIdx.x;
    int pc = 0;
    #pragma unroll
    for (int ks = 0; ks < KS2; ks++) pc += (int)pcpart[((size_t)ks*N1 + n)*BATCH + b];
    int s = K0 - 2*pc;
    unsigned cnt = *zcnt; if (cnt > ZCAP) cnt = ZCAP;
    for (unsigned e = 0; e < cnt; ++e) {       // essentially never taken
        uint64_t key = zlist[2*e];
        if ((int)(key >> 32) == n) {
            uint64_t zm = zlist[2*e+1];
            uint64_t a = ap_t[(size_t)(key & 0xffffffffu)*256 + b];
            s += 2*(int)__popcll(a & zm) - (int)__popcll(zm);
        }
    }
    float a = fp0[n];
    float v = (s >= 0) ? (float)s : a*(float)s;
    __shared__ double rs[256], rq[256];
    rs[b] = v; rq[b] = (double)v*(double)v;
    __syncthreads();
    for (int off=128; off>0; off>>=1){
        if (b<off){ rs[b]+=rs[b+off]; rq[b]+=rq[b+off]; }
        __syncthreads();
    }
    __shared__ double AB[2];
    if (b == 0) {
        double mean = rs[0] / 256.0;
        double var = rq[0] / 256.0 - mean*mean;
        if (var < 0.0) var = 0.0;
        double A = (double)fg0[n] / sqrt(var + 1e-5);
        AB[0] = A; AB[1] = (double)fb0[n] - mean*A;
    }
    __syncthreads();
    double t = fma((double)v, AB[0], AB[1]);
    af[(size_t)n*256 + b] = (t > 0.0) ? 1.f : ((t < 0.0) ? -1.f : 0.f);
}

// ---- fc1 partial dots (k-split) ----
__global__ __launch_bounds__(256) void k_fc1a(const float* __restrict__ af,
        const float* __restrict__ fw1, float* __restrict__ part9)
{
    __shared__ float swL[10][32];
    int ks = blockIdx.x, b = threadIdx.x;
    for (int i = b; i < 320; i += 256) {
        int j = i / 32, kk = i % 32;
        swL[j][kk] = fsign(fw1[j*1024 + ks*32 + kk]);
    }
    __syncthreads();
    float acc[10];
    #pragma unroll
    for (int j=0;j<10;j++) acc[j]=0.f;
    for (int kk = 0; kk < 32; kk++) {
        float a = af[(size_t)(ks*32+kk)*256 + b];
        #pragma unroll
        for (int j=0;j<10;j++) acc[j] += a * swL[j][kk];
    }
    #pragma unroll
    for (int j=0;j<10;j++) part9[((size_t)ks*256 + b)*10 + j] = acc[j];
}

// ---- fc1 finish: prelu, bn over batch, scale ----
__global__ __launch_bounds__(256) void k_fc1b(const float* __restrict__ part9,
        const float* __restrict__ fp1, const float* __restrict__ fg1,
        const float* __restrict__ fb1, const float* __restrict__ scale,
        float* __restrict__ out)
{
    int b = threadIdx.x;
    float v[10];
    #pragma unroll
    for (int j=0;j<10;j++) v[j]=0.f;
    for (int ks=0; ks<32; ks++)
        #pragma unroll
        for (int j=0;j<10;j++) v[j] += part9[((size_t)ks*256+b)*10 + j];
    #pragma unroll
    for (int j=0;j<10;j++){
        float a = fp1[j];
        v[j] = (v[j] >= 0.f) ? v[j] : a*v[j];
    }
    __shared__ double sv[256];
    __shared__ double AB[2][10];
    for (int j=0;j<10;j++){
        sv[b] = (double)v[j];
        __syncthreads();
        for (int off=128;off>0;off>>=1){ if(b<off) sv[b]+=sv[b+off]; __syncthreads(); }
        double mean = sv[0]/256.0;
        __syncthreads();
        double d = (double)v[j]-mean;
        sv[b] = d*d;
        __syncthreads();
        for (int off=128;off>0;off>>=1){ if(b<off) sv[b]+=sv[b+off]; __syncthreads(); }
        if (b==0){
            double var = sv[0]/256.0;
            double A = (double)fg1[j]/sqrt(var+1e-5);
            AB[0][j]=A; AB[1][j]=(double)fb1[j] - mean*A;
        }
        __syncthreads();
    }
    float sc = scale[0];
    #pragma unroll
    for (int j=0;j<10;j++)
        out[b*10+j] = (float)fma((double)v[j], AB[0][j], AB[1][j]) * sc;
}

extern "C" void kernel_launch(void* const* d_in, const int* in_sizes, int n_in,
                              void* d_out, int out_size, void* d_ws, size_t ws_size,
                              hipStream_t stream)
{
    const float* x    = (const float*)d_in[0];
    const float* cw0  = (const float*)d_in[1];
    const float* cp0  = (const float*)d_in[2];
    const float* cg0  = (const float*)d_in[3];
    const float* cb0  = (const float*)d_in[4];
    const float* cw1  = (const float*)d_in[5];
    const float* cp1  = (const float*)d_in[6];
    const float* cg1  = (const float*)d_in[7];
    const float* cb1  = (const float*)d_in[8];
    const float* fw0  = (const float*)d_in[9];
    const float* fp0  = (const float*)d_in[10];
    const float* fg0  = (const float*)d_in[11];
    const float* fb0  = (const float*)d_in[12];
    const float* fw1  = (const float*)d_in[13];
    const float* fp1  = (const float*)d_in[14];
    const float* fg1  = (const float*)d_in[15];
    const float* fb1  = (const float*)d_in[16];
    const float* scale= (const float*)d_in[17];

    char* ws = (char*)d_ws;
    size_t off = 0;
    auto alloc = [&](size_t bytes)->char* {
        char* r = ws + off; off = (off + bytes + 255) & ~(size_t)255; return r; };

    // zeroed-by-k_pack_w1-block0 region: bytes [0, 3328)
    double*   S0    = (double*)alloc(64*8);     // @0
    double*   Q0    = (double*)alloc(64*8);     // @512
    double*   S1    = (double*)alloc(128*8);    // @1024
    double*   Q1    = (double*)alloc(128*8);    // @2048
    unsigned* zcnt  = (unsigned*)alloc(256);    // @3072
    // scratch (fully overwritten each call before use)
    unsigned* lut0  = (unsigned*)alloc(64*4);
    double*   A1B1  = (double*)alloc(256*8);
    int8_t*   h0s   = (int8_t*)alloc((size_t)256*784*64);
    uint64_t* hp    = (uint64_t*)alloc((size_t)256*784*8);
    int16_t*  h1s   = (int16_t*)alloc((size_t)256*128*784*2);
    uint64_t* ap_t  = (uint64_t*)alloc((size_t)KW*256*8);
    uint64_t* wn1   = (uint64_t*)alloc(1152*8);
    uint64_t* wnz1  = (uint64_t*)alloc(1152*8);
    uint64_t* wp    = (uint64_t*)alloc((size_t)N1*KW*8);
    int16_t*  pcpart= (int16_t*)alloc((size_t)KS2*N1*BATCH*2);
    float*    af    = (float*)alloc((size_t)1024*256*4);
    float*    part9 = (float*)alloc((size_t)32*256*10*4);
    uint64_t* zlist = (uint64_t*)alloc((size_t)ZCAP*16);
    (void)ws_size; (void)in_sizes; (void)n_in; (void)out_size;

    k_pack_w1<<<288,   256, 0, stream>>>(cw1, wn1, wnz1, (int*)d_ws);
    k_conv0  <<<256,   256, 0, stream>>>(x, cw0, cp0, h0s, S0, Q0);
    k_bnfin0 <<<1,      64, 0, stream>>>(S0, Q0, cg0, cb0, cp0, lut0);
    k_pack_h0<<<784,   256, 0, stream>>>(h0s, lut0, hp);
    k_conv1  <<<16384, 256, 0, stream>>>(hp, wn1, wnz1, cp1, h1s, S1, Q1);
    k_bnfin  <<<1,     128, 0, stream>>>(S1, Q1, cg1, cb1, A1B1, 128, 1.0/200704.0);
    k_pack_a0<<<256*98,256, 0, stream>>>(h1s, cp1, A1B1, ap_t);
    k_pack_w0<<<2048,  256, 0, stream>>>(fw0, wp, zcnt, zlist);
    k_fc0g   <<<KS2*32,256, 0, stream>>>(wp, ap_t, pcpart);
    k_fc0ep  <<<1024,  256, 0, stream>>>(pcpart, zcnt, zlist, ap_t, fp0, fg0, fb0, af);
    k_fc1a   <<<32,    256, 0, stream>>>(af, fw1, part9);
    k_fc1b   <<<1,     256, 0, stream>>>(part9, fp1, fg1, fb1, scale, (float*)d_out);
}

// Round 5
// 350.578 us; speedup vs baseline: 3.0031x; 1.0128x over previous
//
#include <hip/hip_runtime.h>
#include <stdint.h>

// ---------------------------------------------------------------------------
// Binary net:  conv0(1->64,3x3) -> prelu -> bn -> bin
//              conv1(64->128,3x3) -> prelu -> bn -> bin
//              fc0(100352->1024)  -> prelu -> bn -> bin
//              fc1(1024->10)      -> prelu -> bn -> *scale
// binarize(bn(x)) == sign(v*A_c + B_c)  (A,B from batch stats, f64).
// fc0: weight pack fused INTO the popcount GEMM (each block consumes a
// disjoint 256KB slice of fw0 exactly once -> no packed-weight round trip).
// Interleaved bit order: word j=4Q+c holds elements k=256Q+4i+c at bit i;
// popcount(x^y) is invariant under a common bit permutation, activations
// use the SAME packing.
// ---------------------------------------------------------------------------

static constexpr int BATCH = 256;
static constexpr int K0    = 100352;  // 128*784
static constexpr int KW    = 1568;    // K0/64 words
static constexpr int N1    = 1024;
static constexpr int KS2   = 49;      // k-splits
static constexpr int JW2   = 32;      // words per split (KW/KS2)
static constexpr int SUB2  = 8;       // ap words per LDS subchunk
static constexpr int NS2   = 4;       // JW2/SUB2
static constexpr unsigned ZCAP = 65536;

__device__ __forceinline__ float fsign(float v){
    return (v > 0.f) ? 1.f : ((v < 0.f) ? -1.f : 0.f);
}

// ---- pack conv1 weights + zero the stats/zcnt region (block 0) ----
__global__ __launch_bounds__(256) void k_pack_w1(const float* __restrict__ cw1,
        uint64_t* __restrict__ wn1, uint64_t* __restrict__ wnz1,
        int* __restrict__ zero_region)
{
    if (blockIdx.x == 0) {
        for (int i = threadIdx.x; i < 512; i += 256) zero_region[i] = 0;
    }
    int idx = blockIdx.x*4 + (threadIdx.x >> 6);     // (oc*9 + t)
    int lane = threadIdx.x & 63;                     // lane = in channel
    int oc = idx / 9, t = idx % 9;
    float w = cw1[oc*576 + lane*9 + t];
    uint64_t n = __ballot(w < 0.f);
    uint64_t z = __ballot(w != 0.f);
    if (lane == 0) { wn1[idx] = n; wnz1[idx] = z; }
}

// ---- conv block 0: sign(x) conv3x3 sign(cw0), prelu, accumulate bn stats ----
__global__ __launch_bounds__(256) void k_conv0(const float* __restrict__ x,
        const float* __restrict__ cw0, const float* __restrict__ cp0,
        int8_t* __restrict__ h0s, double* __restrict__ S0, double* __restrict__ Q0)
{
    __shared__ float img[30][30];
    __shared__ float redS[4][64];
    __shared__ float redQ[4][64];
    int b = blockIdx.x;
    int tid = threadIdx.x;
    for (int i = tid; i < 900; i += 256) ((float*)img)[i] = 0.f;
    __syncthreads();
    for (int i = tid; i < 784; i += 256) {
        float v = x[b*784 + i];
        img[1 + i/28][1 + i%28] = fsign(v);
    }
    __syncthreads();
    int lane = tid & 63, wv = tid >> 6;   // lane = out channel
    float wsg[9];
    #pragma unroll
    for (int t = 0; t < 9; t++) wsg[t] = fsign(cw0[lane*9 + t]);
    float a = cp0[lane];
    float accS = 0.f, accQ = 0.f;
    for (int i = 0; i < 196; i++) {
        int p = wv*196 + i;
        int y = p / 28, xx = p % 28;
        float s = 0.f;
        #pragma unroll
        for (int dy = 0; dy < 3; dy++)
            #pragma unroll
            for (int dx = 0; dx < 3; dx++)
                s += img[y+dy][xx+dx] * wsg[dy*3+dx];
        h0s[(size_t)(b*784 + p)*64 + lane] = (int8_t)(int)s;  // exact small int
        float v = (s >= 0.f) ? s : a*s;
        accS += v; accQ += v*v;
    }
    redS[wv][lane] = accS; redQ[wv][lane] = accQ;
    __syncthreads();
    if (tid < 64) {
        double s = (double)redS[0][tid] + redS[1][tid] + redS[2][tid] + redS[3][tid];
        double q = (double)redQ[0][tid] + redQ[1][tid] + redQ[2][tid] + redQ[3][tid];
        atomicAdd(&S0[tid], s);
        atomicAdd(&Q0[tid], q);
    }
}

// ---- pack conv1 input (fused bn0 finalize -> 19-entry LUT per channel) ----
__global__ __launch_bounds__(256) void k_pack_h0(const int8_t* __restrict__ h0s,
        const double* __restrict__ S0, const double* __restrict__ Q0,
        const float* __restrict__ cg0, const float* __restrict__ cb0,
        const float* __restrict__ cp0, uint64_t* __restrict__ hp)
{
    __shared__ unsigned l[64];
    int tid = threadIdx.x;
    if (tid < 64) {
        double mean = S0[tid] * (1.0/200704.0);
        double var  = Q0[tid] * (1.0/200704.0) - mean*mean;
        if (var < 0.0) var = 0.0;
        double A = (double)cg0[tid] / sqrt(var + 1e-5);
        double B = (double)cb0[tid] - mean*A;
        float a = cp0[tid];
        unsigned m = 0;
        for (int s = -9; s <= 9; ++s) {          // conv0 sums in [-9,9]
            float v = (s >= 0) ? (float)s : a*(float)s;
            if (fma((double)v, A, B) < 0.0) m |= 1u << (s + 9);
        }
        l[tid] = m;
    }
    __syncthreads();
    int pixel = blockIdx.x*256 + tid;      // grid 784*256 == 200704 exact
    const int4* p4 = (const int4*)(h0s + (size_t)pixel*64);
    int4 va = p4[0], vb = p4[1], vc = p4[2], vd = p4[3];
    int wa[16] = {va.x,va.y,va.z,va.w, vb.x,vb.y,vb.z,vb.w,
                  vc.x,vc.y,vc.z,vc.w, vd.x,vd.y,vd.z,vd.w};
    unsigned lo = 0, hi = 0;
    #pragma unroll
    for (int wi = 0; wi < 16; ++wi) {
        unsigned w = (unsigned)wa[wi];
        #pragma unroll
        for (int c2 = 0; c2 < 4; ++c2) {
            int ch = wi*4 + c2;
            int s = (int)(signed char)(w >> (8*c2));
            unsigned bit = (l[ch] >> (s + 9)) & 1u;
            if (ch < 32) lo |= bit << ch; else hi |= bit << (ch - 32);
        }
    }
    hp[pixel] = ((uint64_t)hi << 32) | lo;
}

// ---- conv1 via XOR/popcount; bn1 partials to race-free global array ----
__global__ __launch_bounds__(256) void k_conv1(const uint64_t* __restrict__ hp,
        const uint64_t* __restrict__ wn1, const uint64_t* __restrict__ wnz1,
        const float* __restrict__ cp1, int16_t* __restrict__ h1s,
        double* __restrict__ pS1, double* __restrict__ pQ1)
{
    __shared__ float lS[4][8];
    __shared__ float lQ[4][8];
    int bid = blockIdx.x;
    int ocg = bid & 15;
    int ptg = (bid >> 4) & 3;
    int b   = bid >> 6;
    int wv = threadIdx.x >> 6, lane = threadIdx.x & 63;
    int pt = ptg*4 + wv;
    bool active = (pt < 13);
    int p = active ? (pt*64 + lane) : 0;
    bool pvalid = active && (p < 784);
    int y = p / 28, xx = p % 28;
    uint64_t nb[9]; unsigned vmask = 0;
    #pragma unroll
    for (int dy = 0; dy < 3; dy++)
        #pragma unroll
        for (int dx = 0; dx < 3; dx++) {
            int t = dy*3+dx;
            int yy = y + dy - 1, xv = xx + dx - 1;
            bool ok = (yy >= 0 && yy < 28 && xv >= 0 && xv < 28);
            nb[t] = hp[b*784 + (ok ? (yy*28+xv) : 0)];
            if (ok) vmask |= 1u << t;
        }
    #pragma unroll
    for (int o = 0; o < 8; o++) {
        int oc = ocg*8 + o;
        int base = oc*9;
        int acc = 0;
        #pragma unroll
        for (int t = 0; t < 9; t++) {
            uint64_t wn = wn1[base+t], wz = wnz1[base+t];
            if (vmask & (1u<<t))
                acc += (int)__popcll(wz) - 2*(int)__popcll((nb[t] ^ wn) & wz);
        }
        if (pvalid) h1s[((size_t)b*128 + oc)*784 + p] = (int16_t)acc;
        float pr = cp1[oc];
        float v = pvalid ? ((acc >= 0) ? (float)acc : pr*(float)acc) : 0.f;
        float s = v, q = v*v;
        #pragma unroll
        for (int off = 32; off; off >>= 1) {
            s += __shfl_xor(s, off);
            q += __shfl_xor(q, off);
        }
        if (lane == 0) { lS[wv][o] = s; lQ[wv][o] = q; }
    }
    __syncthreads();
    if (threadIdx.x < 16) {
        int o = threadIdx.x & 7;
        bool isQ = threadIdx.x >= 8;
        double v4 = isQ ? ((double)lQ[0][o] + lQ[1][o] + lQ[2][o] + lQ[3][o])
                        : ((double)lS[0][o] + lS[1][o] + lS[2][o] + lS[3][o]);
        double* dst = isQ ? pQ1 : pS1;
        dst[(size_t)(ocg*8 + o)*1024 + (b*4 + ptg)] = v4;
    }
}

// ---- bn1 finalize: parallel reduce partials -> (A,B) per channel ----
__global__ __launch_bounds__(256) void k_bnfin1(const double* __restrict__ pS,
        const double* __restrict__ pQ, const float* __restrict__ g,
        const float* __restrict__ bb, double* __restrict__ AB)
{
    int oc = blockIdx.x;      // 128
    int tid = threadIdx.x;
    double s = 0.0, q = 0.0;
    #pragma unroll
    for (int i = 0; i < 4; ++i) {
        s += pS[(size_t)oc*1024 + tid + 256*i];
        q += pQ[(size_t)oc*1024 + tid + 256*i];
    }
    __shared__ double rs[256], rq[256];
    rs[tid] = s; rq[tid] = q;
    __syncthreads();
    for (int off = 128; off; off >>= 1) {
        if (tid < off) { rs[tid] += rs[tid+off]; rq[tid] += rq[tid+off]; }
        __syncthreads();
    }
    if (tid == 0) {
        double mean = rs[0] * (1.0/200704.0);
        double var  = rq[0] * (1.0/200704.0) - mean*mean;
        if (var < 0.0) var = 0.0;
        double A = (double)g[oc] / sqrt(var + 1e-5);
        AB[oc] = A; AB[128 + oc] = (double)bb[oc] - mean*A;
    }
}

// ---- pack fc0 activations, interleaved order, ap_t[word j][batch b] ----
// word j = 4Q+c, bit i = element k = 256Q + 4i + c  (short4 per lane)
__global__ __launch_bounds__(256) void k_pack_a0(const int16_t* __restrict__ h1s,
        const float* __restrict__ cp1, const double* __restrict__ AB,
        uint64_t* __restrict__ ap_t)
{
    int blk = blockIdx.x;                 // 256*98 blocks
    int b  = blk / 98;
    int qg = blk % 98;
    int wv = threadIdx.x >> 6, lane = threadIdx.x & 63;
    int q  = qg*4 + wv;                   // 0..391
    int k0 = q*256 + lane*4;
    short4 sv = *(const short4*)(h1s + (size_t)b*K0 + k0);
    int oc = k0 / 784;                    // all 4 elements share oc (4 | 784)
    double A = AB[oc], B = AB[128 + oc];
    float a = cp1[oc];
    int ss[4] = {sv.x, sv.y, sv.z, sv.w};
    uint64_t words[4];
    #pragma unroll
    for (int c = 0; c < 4; ++c) {
        float s = (float)ss[c];
        float v = (s >= 0.f) ? s : a*s;
        double t = fma((double)v, A, B);
        words[c] = __ballot(t < 0.0);
    }
    if (lane == 0) {
        #pragma unroll
        for (int c = 0; c < 4; ++c)
            ap_t[(size_t)(4*q + c)*256 + b] = words[c];
    }
}

// ---- fused fc0: stream-pack this block's fw0 slice into LDS, then
//      XOR/popcount GEMM against packed activations ----
__global__ __launch_bounds__(256) void k_fc0g(const float* __restrict__ fw0,
        const uint64_t* __restrict__ ap_t, int16_t* __restrict__ pcpart,
        unsigned* __restrict__ zcnt, uint64_t* __restrict__ zlist)
{
    __shared__ uint64_t wT[32][33];       // +1 pad: kills bank conflicts
    __shared__ uint64_t apL[SUB2][256];
    int ks = blockIdx.x % KS2;            // consecutive blocks walk k (stream)
    int nt = blockIdx.x / KS2;
    int tid = threadIdx.x;
    int wv = tid >> 6, lane = tid & 63;
    int n0 = nt*32, j0 = ks*JW2;
    // ---- stage A: pack 32 rows x 2048 elements (256KB of fw0, read once) ----
    {
        const float* wsrc = fw0 + (size_t)(n0 + wv*8)*K0 + (size_t)(ks*8)*256 + lane*4;
        for (int r8 = 0; r8 < 8; ++r8) {
            const float* rowp = wsrc + (size_t)r8*K0;
            int row = wv*8 + r8;
            #pragma unroll
            for (int qq = 0; qq < 8; ++qq) {
                float4 w = *(const float4*)(rowp + qq*256);
                uint64_t g0 = __ballot(w.x < 0.f);
                uint64_t g1 = __ballot(w.y < 0.f);
                uint64_t g2 = __ballot(w.z < 0.f);
                uint64_t g3 = __ballot(w.w < 0.f);
                uint64_t z0 = __ballot(w.x == 0.f);
                uint64_t z1 = __ballot(w.y == 0.f);
                uint64_t z2 = __ballot(w.z == 0.f);
                uint64_t z3 = __ballot(w.w == 0.f);
                if (lane == 0) {
                    wT[row][qq*4+0] = g0;
                    wT[row][qq*4+1] = g1;
                    wT[row][qq*4+2] = g2;
                    wT[row][qq*4+3] = g3;
                    uint64_t zz[4] = {z0, z1, z2, z3};
                    #pragma unroll
                    for (int c = 0; c < 4; ++c) if (zz[c]) {   // ~never
                        unsigned id = atomicAdd(zcnt, 1u);
                        if (id < ZCAP) {
                            unsigned j = (unsigned)((ks*8 + qq)*4 + c);
                            zlist[2*id]   = ((uint64_t)(unsigned)(n0+row) << 32) | j;
                            zlist[2*id+1] = zz[c];
                        }
                    }
                }
            }
        }
    }
    // ---- stage B: popcount GEMM ----
    int bq = tid & 31;            // b = bq + 32*i
    int nq = tid >> 5;            // n = n0 + nq + 8*k
    int pc[8][4];
    #pragma unroll
    for (int i = 0; i < 8; i++)
        #pragma unroll
        for (int k = 0; k < 4; k++) pc[i][k] = 0;
    for (int c = 0; c < NS2; c++) {
        #pragma unroll
        for (int r = 0; r < SUB2; r++)
            apL[r][tid] = ap_t[(size_t)(j0 + c*SUB2 + r)*256 + tid];
        __syncthreads();                  // covers wT on first pass
        #pragma unroll
        for (int jj = 0; jj < SUB2; jj++) {
            uint64_t aw[8], ww[4];
            #pragma unroll
            for (int i = 0; i < 8; i++) aw[i] = apL[jj][bq + 32*i];
            #pragma unroll
            for (int k = 0; k < 4; k++) ww[k] = wT[nq + 8*k][c*8 + jj];
            #pragma unroll
            for (int i = 0; i < 8; i++)
                #pragma unroll
                for (int k = 0; k < 4; k++)
                    pc[i][k] += (int)__popcll(aw[i] ^ ww[k]);
        }
        __syncthreads();
    }
    #pragma unroll
    for (int k = 0; k < 4; k++) {
        int n = n0 + nq + 8*k;
        #pragma unroll
        for (int i = 0; i < 8; i++)
            pcpart[((size_t)ks*N1 + n)*BATCH + (bq + 32*i)] = (int16_t)pc[i][k];
    }
}

// ---- fc0 epilogue: combine partials + zero-weight corrections, bn, binarize ----
__global__ __launch_bounds__(256) void k_fc0ep(const int16_t* __restrict__ pcpart,
        const unsigned* __restrict__ zcnt, const uint64_t* __restrict__ zlist,
        const uint64_t* __restrict__ ap_t, const float* __restrict__ fp0,
        const float* __restrict__ fg0, const float* __restrict__ fb0,
        float* __restrict__ af)
{
    int n = blockIdx.x, b = threadIdx.x;
    int pc = 0;
    #pragma unroll
    for (int ks = 0; ks < KS2; ks++) pc += (int)pcpart[((size_t)ks*N1 + n)*BATCH + b];
    int s = K0 - 2*pc;
    unsigned cnt = *zcnt; if (cnt > ZCAP) cnt = ZCAP;
    for (unsigned e = 0; e < cnt; ++e) {       // essentially never taken
        uint64_t key = zlist[2*e];
        if ((int)(key >> 32) == n) {
            uint64_t zm = zlist[2*e+1];
            uint64_t a = ap_t[(size_t)(key & 0xffffffffu)*256 + b];
            s += 2*(int)__popcll(a & zm) - (int)__popcll(zm);
        }
    }
    float a = fp0[n];
    float v = (s >= 0) ? (float)s : a*(float)s;
    __shared__ double rs[256], rq[256];
    rs[b] = v; rq[b] = (double)v*(double)v;
    __syncthreads();
    for (int off=128; off>0; off>>=1){
        if (b<off){ rs[b]+=rs[b+off]; rq[b]+=rq[b+off]; }
        __syncthreads();
    }
    __shared__ double AB[2];
    if (b == 0) {
        double mean = rs[0] / 256.0;
        double var = rq[0] / 256.0 - mean*mean;
        if (var < 0.0) var = 0.0;
        double A = (double)fg0[n] / sqrt(var + 1e-5);
        AB[0] = A; AB[1] = (double)fb0[n] - mean*A;
    }
    __syncthreads();
    double t = fma((double)v, AB[0], AB[1]);
    af[(size_t)n*256 + b] = (t > 0.0) ? 1.f : ((t < 0.0) ? -1.f : 0.f);
}

// ---- fc1 partial dots (k-split) ----
__global__ __launch_bounds__(256) void k_fc1a(const float* __restrict__ af,
        const float* __restrict__ fw1, float* __restrict__ part9)
{
    __shared__ float swL[10][32];
    int ks = blockIdx.x, b = threadIdx.x;
    for (int i = b; i < 320; i += 256) {
        int j = i / 32, kk = i % 32;
        swL[j][kk] = fsign(fw1[j*1024 + ks*32 + kk]);
    }
    __syncthreads();
    float acc[10];
    #pragma unroll
    for (int j=0;j<10;j++) acc[j]=0.f;
    for (int kk = 0; kk < 32; kk++) {
        float a = af[(size_t)(ks*32+kk)*256 + b];
        #pragma unroll
        for (int j=0;j<10;j++) acc[j] += a * swL[j][kk];
    }
    #pragma unroll
    for (int j=0;j<10;j++) part9[((size_t)ks*256 + b)*10 + j] = acc[j];
}

// ---- fc1 finish: prelu, bn over batch, scale ----
__global__ __launch_bounds__(256) void k_fc1b(const float* __restrict__ part9,
        const float* __restrict__ fp1, const float* __restrict__ fg1,
        const float* __restrict__ fb1, const float* __restrict__ scale,
        float* __restrict__ out)
{
    int b = threadIdx.x;
    float v[10];
    #pragma unroll
    for (int j=0;j<10;j++) v[j]=0.f;
    for (int ks=0; ks<32; ks++)
        #pragma unroll
        for (int j=0;j<10;j++) v[j] += part9[((size_t)ks*256+b)*10 + j];
    #pragma unroll
    for (int j=0;j<10;j++){
        float a = fp1[j];
        v[j] = (v[j] >= 0.f) ? v[j] : a*v[j];
    }
    __shared__ double sv[256];
    __shared__ double AB[2][10];
    for (int j=0;j<10;j++){
        sv[b] = (double)v[j];
        __syncthreads();
        for (int off=128;off>0;off>>=1){ if(b<off) sv[b]+=sv[b+off]; __syncthreads(); }
        double mean = sv[0]/256.0;
        __syncthreads();
        double d = (double)v[j]-mean;
        sv[b] = d*d;
        __syncthreads();
        for (int off=128;off>0;off>>=1){ if(b<off) sv[b]+=sv[b+off]; __syncthreads(); }
        if (b==0){
            double var = sv[0]/256.0;
            double A = (double)fg1[j]/sqrt(var+1e-5);
            AB[0][j]=A; AB[1][j]=(double)fb1[j] - mean*A;
        }
        __syncthreads();
    }
    float sc = scale[0];
    #pragma unroll
    for (int j=0;j<10;j++)
        out[b*10+j] = (float)fma((double)v[j], AB[0][j], AB[1][j]) * sc;
}

extern "C" void kernel_launch(void* const* d_in, const int* in_sizes, int n_in,
                              void* d_out, int out_size, void* d_ws, size_t ws_size,
                              hipStream_t stream)
{
    const float* x    = (const float*)d_in[0];
    const float* cw0  = (const float*)d_in[1];
    const float* cp0  = (const float*)d_in[2];
    const float* cg0  = (const float*)d_in[3];
    const float* cb0  = (const float*)d_in[4];
    const float* cw1  = (const float*)d_in[5];
    const float* cp1  = (const float*)d_in[6];
    const float* cg1  = (const float*)d_in[7];
    const float* cb1  = (const float*)d_in[8];
    const float* fw0  = (const float*)d_in[9];
    const float* fp0  = (const float*)d_in[10];
    const float* fg0  = (const float*)d_in[11];
    const float* fb0  = (const float*)d_in[12];
    const float* fw1  = (const float*)d_in[13];
    const float* fp1  = (const float*)d_in[14];
    const float* fg1  = (const float*)d_in[15];
    const float* fb1  = (const float*)d_in[16];
    const float* scale= (const float*)d_in[17];

    char* ws = (char*)d_ws;
    size_t off = 0;
    auto alloc = [&](size_t bytes)->char* {
        char* r = ws + off; off = (off + bytes + 255) & ~(size_t)255; return r; };

    // zeroed-by-k_pack_w1-block0 region: bytes [0, 2048)
    double*   S0    = (double*)alloc(64*8);     // @0
    double*   Q0    = (double*)alloc(64*8);     // @512
    unsigned* zcnt  = (unsigned*)alloc(256);    // @1024
    // scratch (fully overwritten each call before use)
    double*   A1B1  = (double*)alloc(256*8);
    double*   pS1   = (double*)alloc((size_t)128*1024*8);
    double*   pQ1   = (double*)alloc((size_t)128*1024*8);
    int8_t*   h0s   = (int8_t*)alloc((size_t)256*784*64);
    uint64_t* hp    = (uint64_t*)alloc((size_t)256*784*8);
    int16_t*  h1s   = (int16_t*)alloc((size_t)256*128*784*2);
    uint64_t* ap_t  = (uint64_t*)alloc((size_t)KW*256*8);
    uint64_t* wn1   = (uint64_t*)alloc(1152*8);
    uint64_t* wnz1  = (uint64_t*)alloc(1152*8);
    int16_t*  pcpart= (int16_t*)alloc((size_t)KS2*N1*BATCH*2);
    float*    af    = (float*)alloc((size_t)1024*256*4);
    float*    part9 = (float*)alloc((size_t)32*256*10*4);
    uint64_t* zlist = (uint64_t*)alloc((size_t)ZCAP*16);
    (void)ws_size; (void)in_sizes; (void)n_in; (void)out_size;

    k_pack_w1<<<288,     256, 0, stream>>>(cw1, wn1, wnz1, (int*)d_ws);
    k_conv0  <<<256,     256, 0, stream>>>(x, cw0, cp0, h0s, S0, Q0);
    k_pack_h0<<<784,     256, 0, stream>>>(h0s, S0, Q0, cg0, cb0, cp0, hp);
    k_conv1  <<<16384,   256, 0, stream>>>(hp, wn1, wnz1, cp1, h1s, pS1, pQ1);
    k_bnfin1 <<<128,     256, 0, stream>>>(pS1, pQ1, cg1, cb1, A1B1);
    k_pack_a0<<<256*98,  256, 0, stream>>>(h1s, cp1, A1B1, ap_t);
    k_fc0g   <<<KS2*32,  256, 0, stream>>>(fw0, ap_t, pcpart, zcnt, zlist);
    k_fc0ep  <<<1024,    256, 0, stream>>>(pcpart, zcnt, zlist, ap_t, fp0, fg0, fb0, af);
    k_fc1a   <<<32,      256, 0, stream>>>(af, fw1, part9);
    k_fc1b   <<<1,       256, 0, stream>>>(part9, fp1, fg1, fb1, scale, (float*)d_out);
}